// Round 7
// baseline (6594.562 us; speedup 1.0000x reference)
//
#include <hip/hip_runtime.h>
#include <hip/hip_bf16.h>
#include <cstdint>

// B=8, N=8192, S=1024, C=64
// branch0: r=0.4, K=32, layers 64x67, 64x64, 128x64
// branch1: r=0.8, K=64, layers 64x67, 128x64, 256x128

typedef __attribute__((ext_vector_type(8))) short short8;
typedef __attribute__((ext_vector_type(4))) float f32x4;
typedef __attribute__((ext_vector_type(2))) float f32x2;

__device__ __forceinline__ float bf2f(unsigned short u) {
    return __uint_as_float(((unsigned)u) << 16);
}
__device__ __forceinline__ unsigned short f2bf(float f) {
    unsigned u = __float_as_uint(f);
    return (unsigned short)((u + 0x7fffu + ((u >> 16) & 1u)) >> 16);  // RNE
}

// Wave-64 max reductions, result in lane 63. bound_ctrl=1: out-of-bounds source
// lanes read 0, which is a valid identity here (f32 operands are >=0 squared
// distances; u32 operands are complemented indices with 0 = "no candidate").
__device__ __forceinline__ float wave_red_max_f32_nn(float v) {
#define DPPSTEP(ctrl)                                                            \
    {                                                                            \
        int _t = __builtin_amdgcn_mov_dpp(__float_as_int(v), ctrl, 0xf, 0xf, true); \
        v = fmaxf(v, __int_as_float(_t));                                        \
    }
    DPPSTEP(0x111) DPPSTEP(0x112) DPPSTEP(0x114) DPPSTEP(0x118) DPPSTEP(0x142) DPPSTEP(0x143)
#undef DPPSTEP
    return v;
}
__device__ __forceinline__ unsigned wave_red_max_u32_nn(unsigned v) {
#define DPPSTEP(ctrl)                                                              \
    {                                                                              \
        unsigned _t = (unsigned)__builtin_amdgcn_mov_dpp((int)v, ctrl, 0xf, 0xf, true); \
        v = v > _t ? v : _t;                                                       \
    }
    DPPSTEP(0x111) DPPSTEP(0x112) DPPSTEP(0x114) DPPSTEP(0x118) DPPSTEP(0x142) DPPSTEP(0x143)
#undef DPPSTEP
    return v;
}
__device__ __forceinline__ unsigned long long u64max(unsigned long long a, unsigned long long b) {
    return a > b ? a : b;
}
__device__ __forceinline__ unsigned u32max(unsigned a, unsigned b) { return a > b ? a : b; }

// ---------------- workspace layout (bytes); peak = 224,395,264 ------------------
static const size_t OFF_WBF   = 0;          // packed bf16 weights, 65536 elems (128 KB)
static const size_t OFF_STATS = 262144;     // 704 ch * 128 slots * 2 * 4B
static const size_t STATS_BYTES = 720896;
static const size_t OFF_CTR   = 983040;     // 6 ticket counters (zeroed with stats)
static const size_t OFF_AFF   = 1048576;    // per-layer scale/shift
static const size_t OFF_IDX0  = 2097152;    // 8*1024*32 ints
static const size_t OFF_IDX1  = 3145728;    // 8*1024*64 ints
static const size_t OFF_MX    = 5242880;    // 256*8192 fp32
static const size_t OFF_MN    = 13631488;
static const size_t OFF_Y0    = 22020096;   // bf16 X^T [NCOL][64]  (max 67 MB)
static const size_t OFF_Y1    = 90177536;   // bf16 X^T [NCOL][128] (max 134 MB)
static const size_t OFF_FEATT = 211812352;  // bf16 [8*8192][96] = 12.58 MB, overlaps Y1 tail
// (featTp last read in br1-L0; Y1 beyond 121.6 MB only written by br1-L1, which runs later)

// ---------------- fused pre-kernel: FPS (blocks 0..7) + feat transpose (8..1031)
//                  + weight pack (1032..1159), all concurrent on different CUs ----
__global__ __launch_bounds__(512) void fused_pre(
    const float* __restrict__ xyz, const float* __restrict__ feat,
    float* __restrict__ newxyz, unsigned short* __restrict__ ft,
    const float* __restrict__ w0, const float* __restrict__ w1, const float* __restrict__ w2,
    const float* __restrict__ w3, const float* __restrict__ w4, const float* __restrict__ w5,
    unsigned short* __restrict__ wb) {
    __shared__ union alignas(16) SM {
        struct {
            f32x4 ptsP[8200];  // (x,y,z,0) -> single ds_read_b128 centroid fetch
            float ldsM[16][3];
            float meanv[3];
            unsigned long long sKey[2][8];
            float cbuf[3072];
        } f;
        float tile[64][65];
    } sm;
    const int tid = threadIdx.x;

    if (blockIdx.x >= 1032) {
        // ---- weight pack: w[M][K] f32 -> wb[Mp][Kp] bf16 (zero pad) ----
        int id = (int)(blockIdx.x - 1032) * 512 + tid;  // 0..65535
        const int psz[6] = {6144, 4096, 8192, 6144, 8192, 32768};
        const int Kp[6] = {96, 64, 64, 96, 64, 128};
        const int Ks[6] = {67, 64, 64, 67, 64, 128};
        const float* wp[6] = {w0, w1, w2, w3, w4, w5};
        int off = 0;
        for (int l = 0; l < 6; ++l) {
            if (id < off + psz[l]) {
                int e = id - off;
                int m = e / Kp[l], k = e - m * Kp[l];
                float v = (k < Ks[l]) ? wp[l][m * Ks[l] + k] : 0.f;
                wb[id] = f2bf(v);
                return;
            }
            off += psz[l];
        }
        return;
    }

    if (blockIdx.x >= 8) {
        // ---- featTp: [8][8192][96] bf16; c0..2 = xyz, c3..66 = feat, rest 0 ----
        int tb = (int)blockIdx.x - 8;  // 0..1023
        int b = tb >> 7;
        int j0 = (tb & 127) * 64;
#pragma unroll
        for (int i = 0; i < 8; ++i) {
            int e = i * 512 + tid;
            int c = e >> 6, j = e & 63;
            sm.tile[j][c] = feat[((size_t)b * 64 + c) * 8192 + j0 + j];
        }
        __syncthreads();
#pragma unroll
        for (int i = 0; i < 8; ++i) {
            int e = i * 512 + tid;
            int j = e >> 6, c = e & 63;
            ft[((size_t)(b * 8192 + j0 + j)) * 96 + 3 + c] = f2bf(sm.tile[j][c]);
        }
        if (tid < 64) {
            int j = tid;
            size_t base = ((size_t)(b * 8192 + j0 + j)) * 96;
            const float* xp = xyz + ((size_t)b * 8192 + j0 + j) * 3;
            ft[base + 0] = f2bf(xp[0]);
            ft[base + 1] = f2bf(xp[1]);
            ft[base + 2] = f2bf(xp[2]);
        } else if (tid < 128) {
            int j = tid - 64;
            size_t base = ((size_t)(b * 8192 + j0 + j)) * 96;
            for (int c = 67; c < 96; ++c) ft[base + c] = 0;
        }
        return;
    }

    // ---- FPS: 8 waves, 16 pts/thread as 8 float2 pairs, forced v_pk_* math ----
    const int b = blockIdx.x;
    const int t = tid;
    const int lane = t & 63, wv = t >> 6;
    const float* xb = xyz + (size_t)b * 8192 * 3;

    f32x2 px[8], py[8], pz[8], d[8];
#pragma unroll
    for (int k = 0; k < 8; ++k) {
        int q0 = t + 512 * (2 * k);
        int q1 = t + 512 * (2 * k + 1);
        px[k].x = xb[q0 * 3 + 0]; px[k].y = xb[q1 * 3 + 0];
        py[k].x = xb[q0 * 3 + 1]; py[k].y = xb[q1 * 3 + 1];
        pz[k].x = xb[q0 * 3 + 2]; pz[k].y = xb[q1 * 3 + 2];
        d[k].x = 1e10f; d[k].y = 1e10f;
        f32x4 p0; p0.x = px[k].x; p0.y = py[k].x; p0.z = pz[k].x; p0.w = 0.f;
        f32x4 p1; p1.x = px[k].y; p1.y = py[k].y; p1.z = pz[k].y; p1.w = 0.f;
        sm.f.ptsP[q0 + 1] = p0;
        sm.f.ptsP[q1 + 1] = p1;
    }
    // complemented indices for argmax tie-break (8192 - idx), precomputed
    unsigned cix[8], ciy[8];
#pragma unroll
    for (int k = 0; k < 8; ++k) {
        cix[k] = 8191u - (unsigned)t - 1024u * k;  // idx = t+512*(2k)+1
        ciy[k] = cix[k] - 512u;                    // idx = t+512*(2k+1)+1
    }
    // ---- mean: bit-identical replication of the v1 1024-partial tree ----
    float sxA = 0.f, syA = 0.f, szA = 0.f;
    float sxB = 0.f, syB = 0.f, szB = 0.f;
    int uA = (t + 1023) & 1023;
    int uB = (t + 511) & 1023;
#pragma unroll
    for (int j = 0; j < 8; ++j) {
        int ia = uA + 1024 * j;
        int ib = uB + 1024 * j;
        sxA += xb[ia * 3 + 0]; syA += xb[ia * 3 + 1]; szA += xb[ia * 3 + 2];
        sxB += xb[ib * 3 + 0]; syB += xb[ib * 3 + 1]; szB += xb[ib * 3 + 2];
    }
#pragma unroll
    for (int off = 32; off; off >>= 1) {
        sxA += __shfl_xor(sxA, off, 64);
        syA += __shfl_xor(syA, off, 64);
        szA += __shfl_xor(szA, off, 64);
        sxB += __shfl_xor(sxB, off, 64);
        syB += __shfl_xor(syB, off, 64);
        szB += __shfl_xor(szB, off, 64);
    }
    if (lane == 0) {
        sm.f.ldsM[wv][0] = sxA; sm.f.ldsM[wv][1] = syA; sm.f.ldsM[wv][2] = szA;
        sm.f.ldsM[wv + 8][0] = sxB; sm.f.ldsM[wv + 8][1] = syB; sm.f.ldsM[wv + 8][2] = szB;
    }
    __syncthreads();
    if (t < 3) {
        float s = 0.f;
        for (int w = 0; w < 16; ++w) s += sm.f.ldsM[w][t];
        sm.f.meanv[t] = s * (1.f / 8192.f);
    }
    __syncthreads();
    float cx = sm.f.meanv[0], cy = sm.f.meanv[1], cz = sm.f.meanv[2];
    const float mmx = cx, mmy = cy, mmz = cz;  // mean point (pts idx 0), owned by t0
    float dm = 1e10f;
    if (t == 0) {
        f32x4 pm; pm.x = cx; pm.y = cy; pm.z = cz; pm.w = 0.f;
        sm.f.ptsP[0] = pm;
    }
    __syncthreads();

    for (int it = 0; it < 1024; ++it) {
        if (t == 0) {
            sm.f.cbuf[it * 3 + 0] = cx;
            sm.f.cbuf[it * 3 + 1] = cy;
            sm.f.cbuf[it * 3 + 2] = cz;
        }
        // negated centroid (fneg is bit-exact; a-b == a+(-b) in IEEE)
        f32x2 nc0, nc1, nc2;
        nc0.x = -cx; nc0.y = -cx;
        nc1.x = -cy; nc1.y = -cy;
        nc2.x = -cz; nc2.y = -cz;
        float vmax = 0.f;  // d >= 0 always
#pragma unroll
        for (int k = 0; k < 8; ++k) {
            f32x2 dx, dy, dz, xx, yy, zz, s1, dd;
            asm("v_pk_add_f32 %0, %1, %2" : "=v"(dx) : "v"(px[k]), "v"(nc0));
            asm("v_pk_add_f32 %0, %1, %2" : "=v"(dy) : "v"(py[k]), "v"(nc1));
            asm("v_pk_add_f32 %0, %1, %2" : "=v"(dz) : "v"(pz[k]), "v"(nc2));
            asm("v_pk_mul_f32 %0, %1, %1" : "=v"(xx) : "v"(dx));
            asm("v_pk_mul_f32 %0, %1, %1" : "=v"(yy) : "v"(dy));
            asm("v_pk_mul_f32 %0, %1, %1" : "=v"(zz) : "v"(dz));
            asm("v_pk_add_f32 %0, %1, %2" : "=v"(s1) : "v"(xx), "v"(yy));
            asm("v_pk_add_f32 %0, %1, %2" : "=v"(dd) : "v"(s1), "v"(zz));
            float n0 = fminf(d[k].x, dd.x);
            float n1 = fminf(d[k].y, dd.y);
            d[k].x = n0; d[k].y = n1;
            vmax = fmaxf(vmax, fmaxf(n0, n1));
        }
        if (t == 0) {
            float dx = __fsub_rn(mmx, cx);
            float dy = __fsub_rn(mmy, cy);
            float dz = __fsub_rn(mmz, cz);
            float dd = __fadd_rn(__fadd_rn(__fmul_rn(dx, dx), __fmul_rn(dy, dy)), __fmul_rn(dz, dz));
            dm = fminf(dm, dd);
            vmax = fmaxf(vmax, dm);
        }
        float wm = wave_red_max_f32_nn(vmax);
        float bmaxw = __int_as_float(__builtin_amdgcn_readlane(__float_as_int(wm), 63));
        // first-occurrence index = max complemented index among ties
        unsigned best = 0u;
#pragma unroll
        for (int k = 0; k < 8; ++k) {
            best = u32max(best, (d[k].x == bmaxw) ? cix[k] : 0u);
            best = u32max(best, (d[k].y == bmaxw) ? ciy[k] : 0u);
        }
        if (t == 0 && dm == bmaxw) best = 8192u;  // mean point: comp idx 8192 (max)
        unsigned wbest = wave_red_max_u32_nn(best);
        unsigned miw = (unsigned)__builtin_amdgcn_readlane((int)wbest, 63);
        int par = it & 1;
        if (lane == 0)
            sm.f.sKey[par][wv] = ((unsigned long long)__float_as_uint(bmaxw) << 32) |
                                 (unsigned long long)miw;
        __syncthreads();  // the ONLY barrier per iteration (parity-double-buffered slots)
        unsigned long long ka[8];
#pragma unroll
        for (int i = 0; i < 8; ++i) ka[i] = sm.f.sKey[par][i];  // same-address broadcasts
        unsigned long long p0 = u64max(ka[0], ka[1]), p1 = u64max(ka[2], ka[3]);
        unsigned long long p2 = u64max(ka[4], ka[5]), p3 = u64max(ka[6], ka[7]);
        unsigned long long kk = u64max(u64max(p0, p1), u64max(p2, p3));
        int far = 8192 - (int)(unsigned)(kk & 0xffffffffull);
        f32x4 c4 = sm.f.ptsP[far];  // one ds_read_b128 broadcast
        cx = c4.x; cy = c4.y; cz = c4.z;
    }
    __syncthreads();
    float* ob = newxyz + (size_t)b * 3072;
#pragma unroll
    for (int i = 0; i < 6; ++i) ob[t + 512 * i] = sm.f.cbuf[t + 512 * i];
}

// ---------------- merged ball query: blocks 0..2047 br0 (K=32), 2048..4095 br1 --
__global__ void ball_query2(const float* __restrict__ xyz, const float* __restrict__ newxyz,
                            int* __restrict__ idx0, int* __restrict__ idx1) {
    int bid = blockIdx.x;
    int br = (bid >= 2048);
    int K = br ? 64 : 32;
    float r2 = br ? (0.8f * 0.8f) : (0.4f * 0.4f);
    int* idxout = br ? idx1 : idx0;
    int wid = (((bid & 2047) * 256) + threadIdx.x) >> 6;  // query id, 0..8191
    int lane = threadIdx.x & 63;
    int b = wid >> 10;
    const float* q = newxyz + (size_t)wid * 3;
    float qx = q[0], qy = q[1], qz = q[2];
    const float* xb = xyz + (size_t)b * 8192 * 3;
    int* out = idxout + (size_t)wid * K;
    int count = 0;
    int first = 0;
    for (int base = 0; base < 8192 && count < K; base += 64) {
        int j = base + lane;
        float dx = __fsub_rn(xb[j * 3 + 0], qx);
        float dy = __fsub_rn(xb[j * 3 + 1], qy);
        float dz = __fsub_rn(xb[j * 3 + 2], qz);
        float d2 = __fadd_rn(__fadd_rn(__fmul_rn(dx, dx), __fmul_rn(dy, dy)), __fmul_rn(dz, dz));
        bool in = d2 < r2;
        unsigned long long m = __ballot(in);
        if (count == 0 && m) first = base + __ffsll((long long)m) - 1;
        if (in) {
            int pos = count + __popcll(m & ((1ull << lane) - 1ull));
            if (pos < K) out[pos] = j;
        }
        count += __popcll(m);
    }
    if (count < K) {
        int fillv = (count > 0) ? first : 0;
        for (int p = count + lane; p < K; p += 64) out[p] = fillv;
    }
}

// ---------------- MFMA GEMM with LDS B-staging + inline ticket finalize ---------
template <int Mp, int Kp, int IN_MODE, int OUT_MODE, int KSH>
__global__ __launch_bounds__(256) void gemm_mfma(
    const unsigned short* __restrict__ Wb, const unsigned short* __restrict__ Xin,
    const float* __restrict__ aff, const int* __restrict__ idx,
    const unsigned short* __restrict__ ftp, const float* __restrict__ newxyz,
    unsigned short* __restrict__ Yout, float* __restrict__ MX, float* __restrict__ MN,
    float* __restrict__ statS, float* __restrict__ statQ,
    const float* __restrict__ gW, const float* __restrict__ bW, float* __restrict__ affOut,
    float invCount, int* __restrict__ ctr, int nTot) {
    constexpr int MT = Mp / 64;
    constexpr int KS = Kp / 32;
    constexpr int Kpad = Kp + 8;
    constexpr int KC = Kp / 8;
    constexpr int CPT = (64 * KC) / 256;
    __shared__ unsigned short Bs[64 * Kpad];
    __shared__ float sAux[256];
    __shared__ int lastFlag;
    int* sAuxI = (int*)sAux;

    const int tid = threadIdx.x;
    const int w = tid >> 6;
    const int lane = tid & 63;
    const int n = lane & 15;
    const int quad = lane >> 4;
    const int rbase = w * (Mp / 4);
    const long col0 = (long)blockIdx.x * 64;

    short8 a[MT][KS];
#pragma unroll
    for (int mt = 0; mt < MT; ++mt)
#pragma unroll
        for (int ks = 0; ks < KS; ++ks)
            a[mt][ks] = *(const short8*)(Wb + (size_t)(rbase + mt * 16 + n) * Kp + ks * 32 + quad * 8);

    if constexpr (IN_MODE == 0) {
        if (tid < 64) {
            long colg = col0 + tid;
            sAuxI[tid] = idx[colg];
            long sk = colg >> KSH;
            sAux[64 + tid] = newxyz[sk * 3 + 0];
            sAux[128 + tid] = newxyz[sk * 3 + 1];
            sAux[192 + tid] = newxyz[sk * 3 + 2];
        }
    } else {
        if (tid < 2 * Kp) sAux[tid] = aff[tid];
    }
    __syncthreads();

    if constexpr (IN_MODE == 0) {
        const int bb = (int)(col0 >> (KSH + 10));
#pragma unroll
        for (int i = 0; i < CPT; ++i) {
            int c = i * 256 + tid;
            int col = c / KC;
            int kc = c - col * KC;
            int j = sAuxI[col];
            short8 v = *(const short8*)(ftp + ((long)(bb * 8192 + j)) * 96 + kc * 8);
            if (kc == 0) {
                v[0] = (short)f2bf(bf2f((unsigned short)v[0]) - sAux[64 + col]);
                v[1] = (short)f2bf(bf2f((unsigned short)v[1]) - sAux[128 + col]);
                v[2] = (short)f2bf(bf2f((unsigned short)v[2]) - sAux[192 + col]);
            }
            *(short8*)(&Bs[col * Kpad + kc * 8]) = v;
        }
    } else {
#pragma unroll
        for (int i = 0; i < CPT; ++i) {
            int c = i * 256 + tid;
            int col = c / KC;
            int kc = c - col * KC;
            short8 raw = *(const short8*)(Xin + (col0 + col) * (long)Kp + kc * 8);
            short8 v;
#pragma unroll
            for (int e = 0; e < 8; ++e) {
                float xf = bf2f((unsigned short)raw[e]);
                xf = fmaxf(fmaf(xf, sAux[kc * 8 + e], sAux[Kp + kc * 8 + e]), 0.f);
                v[e] = (short)f2bf(xf);
            }
            *(short8*)(&Bs[col * Kpad + kc * 8]) = v;
        }
    }
    __syncthreads();

    f32x4 acc[MT][4];
#pragma unroll
    for (int mt = 0; mt < MT; ++mt)
#pragma unroll
        for (int nt = 0; nt < 4; ++nt)
#pragma unroll
            for (int r = 0; r < 4; ++r) acc[mt][nt][r] = 0.f;

#pragma unroll
    for (int ks = 0; ks < KS; ++ks) {
#pragma unroll
        for (int nt = 0; nt < 4; ++nt) {
            short8 bfr = *(const short8*)(&Bs[(nt * 16 + n) * Kpad + ks * 32 + quad * 8]);
#pragma unroll
            for (int mt = 0; mt < MT; ++mt)
                acc[mt][nt] = __builtin_amdgcn_mfma_f32_16x16x32_bf16(a[mt][ks], bfr, acc[mt][nt], 0, 0, 0);
        }
    }

    const int slot = (int)(blockIdx.x & 127);
#pragma unroll
    for (int mt = 0; mt < MT; ++mt)
#pragma unroll
        for (int r = 0; r < 4; ++r) {
            float s = 0.f, q = 0.f;
#pragma unroll
            for (int nt = 0; nt < 4; ++nt) {
                float v = acc[mt][nt][r];
                s += v;
                q = fmaf(v, v, q);
            }
#pragma unroll
            for (int off = 1; off < 16; off <<= 1) {
                s += __shfl_xor(s, off, 16);
                q += __shfl_xor(q, off, 16);
            }
            if (n == 0) {
                int ch = rbase + mt * 16 + quad * 4 + r;
                atomicAdd(statS + (size_t)ch * 128 + slot, s);
                atomicAdd(statQ + (size_t)ch * 128 + slot, q);
            }
        }

    if constexpr (OUT_MODE == 0) {
#pragma unroll
        for (int mt = 0; mt < MT; ++mt)
#pragma unroll
            for (int nt = 0; nt < 4; ++nt) {
                long col = col0 + nt * 16 + n;
                unsigned p0 = f2bf(acc[mt][nt][0]) | ((unsigned)f2bf(acc[mt][nt][1]) << 16);
                unsigned p1 = f2bf(acc[mt][nt][2]) | ((unsigned)f2bf(acc[mt][nt][3]) << 16);
                uint2 st; st.x = p0; st.y = p1;
                *(uint2*)(Yout + col * Mp + rbase + mt * 16 + quad * 4) = st;
            }
    } else {
#pragma unroll
        for (int mt = 0; mt < MT; ++mt)
#pragma unroll
            for (int r = 0; r < 4; ++r) {
                if constexpr (KSH == 6) {
                    float mx = acc[mt][0][r], mn = acc[mt][0][r];
#pragma unroll
                    for (int nt = 1; nt < 4; ++nt) {
                        mx = fmaxf(mx, acc[mt][nt][r]);
                        mn = fminf(mn, acc[mt][nt][r]);
                    }
#pragma unroll
                    for (int off = 1; off < 16; off <<= 1) {
                        mx = fmaxf(mx, __shfl_xor(mx, off, 16));
                        mn = fminf(mn, __shfl_xor(mn, off, 16));
                    }
                    if (n == 0) {
                        int ch = rbase + mt * 16 + quad * 4 + r;
                        long g = col0 >> 6;
                        MX[(long)ch * 8192 + g] = mx;
                        MN[(long)ch * 8192 + g] = mn;
                    }
                } else {
#pragma unroll
                    for (int gh = 0; gh < 2; ++gh) {
                        float mx = fmaxf(acc[mt][2 * gh][r], acc[mt][2 * gh + 1][r]);
                        float mn = fminf(acc[mt][2 * gh][r], acc[mt][2 * gh + 1][r]);
#pragma unroll
                        for (int off = 1; off < 16; off <<= 1) {
                            mx = fmaxf(mx, __shfl_xor(mx, off, 16));
                            mn = fminf(mn, __shfl_xor(mn, off, 16));
                        }
                        if (n == 0) {
                            int ch = rbase + mt * 16 + quad * 4 + r;
                            long g = (col0 >> 5) + gh;
                            MX[(long)ch * 8192 + g] = mx;
                            MN[(long)ch * 8192 + g] = mn;
                        }
                    }
                }
            }
    }

    // ---- inline finalize: last-finishing block computes BN affine constants ----
    __threadfence();
    if (tid == 0) lastFlag = (atomicAdd(ctr, 1) == nTot - 1) ? 1 : 0;
    __syncthreads();
    if (lastFlag) {
        for (int c = tid; c < Mp; c += 256) {
            float s = 0.f, q = 0.f;
            for (int k2 = 0; k2 < 128; ++k2) {
                // agent-scope loads: coherent with other XCDs' atomics (no kernel-
                // boundary flush inside a kernel)
                s += __hip_atomic_load(&statS[(size_t)c * 128 + k2], __ATOMIC_RELAXED,
                                       __HIP_MEMORY_SCOPE_AGENT);
                q += __hip_atomic_load(&statQ[(size_t)c * 128 + k2], __ATOMIC_RELAXED,
                                       __HIP_MEMORY_SCOPE_AGENT);
            }
            float mean = s * invCount;
            float var = fmaxf(q * invCount - mean * mean, 0.f);
            float sc = gW[c] / sqrtf(var + 1e-5f);
            float sh = bW[c] - mean * sc;
            affOut[c] = sc;
            affOut[Mp + c] = sh;
        }
    }
}

// ---------------- final output -------------------------------------------------
__global__ void final_out_kernel(const float* __restrict__ MX, const float* __restrict__ MN,
                                 const float* __restrict__ aff, float* __restrict__ out1,
                                 int Cout, int cOff) {
    long i = (long)blockIdx.x * 256 + threadIdx.x;
    int c = (int)(i >> 13);
    int gidx = (int)(i & 8191);
    int b = gidx >> 10, s = gidx & 1023;
    float sc = aff[c], sh = aff[Cout + c];
    float v = fmaxf(fmaxf(sc * MX[i] + sh, sc * MN[i] + sh), 0.f);
    out1[((long)b * 384 + cOff + c) * 1024 + s] = v;
}

// ---------------- host ---------------------------------------------------------
extern "C" void kernel_launch(void* const* d_in, const int* in_sizes, int n_in,
                              void* d_out, int out_size, void* d_ws, size_t ws_size,
                              hipStream_t stream) {
    const float* xyz = (const float*)d_in[0];
    const float* feat = (const float*)d_in[1];
    const float *W[6], *G[6], *Bi[6];
    for (int l = 0; l < 6; ++l) {
        W[l] = (const float*)d_in[2 + l * 3];
        G[l] = (const float*)d_in[3 + l * 3];
        Bi[l] = (const float*)d_in[4 + l * 3];
    }
    char* ws = (char*)d_ws;
    float* out0 = (float*)d_out;
    float* out1 = (float*)d_out + 24576;

    unsigned short* wb = (unsigned short*)(ws + OFF_WBF);
    float* stats = (float*)(ws + OFF_STATS);
    int* ctr = (int*)(ws + OFF_CTR);
    float* affine = (float*)(ws + OFF_AFF);
    int* idx0 = (int*)(ws + OFF_IDX0);
    int* idx1 = (int*)(ws + OFF_IDX1);
    float* mx = (float*)(ws + OFF_MX);
    float* mn = (float*)(ws + OFF_MN);
    unsigned short* y0 = (unsigned short*)(ws + OFF_Y0);
    unsigned short* y1 = (unsigned short*)(ws + OFF_Y1);
    unsigned short* ftp = (unsigned short*)(ws + OFF_FEATT);

    hipMemsetAsync(stats, 0, STATS_BYTES + 64, stream);  // stats + ticket counters
    fused_pre<<<1160, 512, 0, stream>>>(xyz, feat, out0, ftp, W[0], W[1], W[2], W[3], W[4],
                                        W[5], wb);
    ball_query2<<<4096, 256, 0, stream>>>(xyz, out0, idx0, idx1);

    const int wOff[6] = {0, 6144, 10240, 18432, 24576, 32768};
    int stOff[6], afOff[6];
    {
        const int Cs[6] = {64, 64, 128, 64, 128, 256};
        int so = 0, ao = 0;
        for (int l = 0; l < 6; ++l) {
            stOff[l] = so; so += Cs[l] * 256;
            afOff[l] = ao; ao += Cs[l] * 2;
        }
    }

    for (int br = 0; br < 2; ++br) {
        const int K = br ? 64 : 32;
        const long NCOL = 8L * 1024 * K;
        int* idx = br ? idx1 : idx0;
        const int l0 = br * 3, l1 = br * 3 + 1, l2 = br * 3 + 2;
        const int M2 = br ? 256 : 128;
        const float invCount = 1.f / (float)NCOL;
        const int nblk = (int)(NCOL / 64);

        if (br == 0) {
            gemm_mfma<64, 96, 0, 0, 5><<<nblk, 256, 0, stream>>>(
                wb + wOff[l0], nullptr, nullptr, idx, ftp, out0, y0, nullptr, nullptr,
                stats + stOff[l0], stats + stOff[l0] + 64 * 128, G[l0], Bi[l0],
                affine + afOff[l0], invCount, ctr + l0, nblk);
            gemm_mfma<64, 64, 1, 0, 5><<<nblk, 256, 0, stream>>>(
                wb + wOff[l1], y0, affine + afOff[l0], nullptr, nullptr, nullptr, y1, nullptr,
                nullptr, stats + stOff[l1], stats + stOff[l1] + 64 * 128, G[l1], Bi[l1],
                affine + afOff[l1], invCount, ctr + l1, nblk);
            gemm_mfma<128, 64, 1, 1, 5><<<nblk, 256, 0, stream>>>(
                wb + wOff[l2], y1, affine + afOff[l1], nullptr, nullptr, nullptr, nullptr, mx, mn,
                stats + stOff[l2], stats + stOff[l2] + 128 * 128, G[l2], Bi[l2],
                affine + afOff[l2], invCount, ctr + l2, nblk);
        } else {
            gemm_mfma<64, 96, 0, 0, 6><<<nblk, 256, 0, stream>>>(
                wb + wOff[l0], nullptr, nullptr, idx, ftp, out0, y0, nullptr, nullptr,
                stats + stOff[l0], stats + stOff[l0] + 64 * 128, G[l0], Bi[l0],
                affine + afOff[l0], invCount, ctr + l0, nblk);
            gemm_mfma<128, 64, 1, 0, 6><<<nblk, 256, 0, stream>>>(
                wb + wOff[l1], y0, affine + afOff[l0], nullptr, nullptr, nullptr, y1, nullptr,
                nullptr, stats + stOff[l1], stats + stOff[l1] + 128 * 128, G[l1], Bi[l1],
                affine + afOff[l1], invCount, ctr + l1, nblk);
            gemm_mfma<256, 128, 1, 1, 6><<<nblk, 256, 0, stream>>>(
                wb + wOff[l2], y1, affine + afOff[l1], nullptr, nullptr, nullptr, nullptr, mx, mn,
                stats + stOff[l2], stats + stOff[l2] + 256 * 128, G[l2], Bi[l2],
                affine + afOff[l2], invCount, ctr + l2, nblk);
        }

        final_out_kernel<<<(M2 * 8192) / 256, 256, 0, stream>>>(mx, mn, affine + afOff[l2], out1,
                                                                M2, br ? 128 : 0);
    }
}

// Round 8
// 1764.773 us; speedup vs baseline: 3.7368x; 3.7368x over previous
//
#include <hip/hip_runtime.h>
#include <hip/hip_bf16.h>
#include <cstdint>

// B=8, N=8192, S=1024, C=64
// branch0: r=0.4, K=32, layers 64x67, 64x64, 128x64
// branch1: r=0.8, K=64, layers 64x67, 128x64, 256x128

typedef __attribute__((ext_vector_type(8))) short short8;
typedef __attribute__((ext_vector_type(4))) float f32x4;
typedef __attribute__((ext_vector_type(2))) float f32x2;

__device__ __forceinline__ float bf2f(unsigned short u) {
    return __uint_as_float(((unsigned)u) << 16);
}
__device__ __forceinline__ unsigned short f2bf(float f) {
    unsigned u = __float_as_uint(f);
    return (unsigned short)((u + 0x7fffu + ((u >> 16) & 1u)) >> 16);  // RNE
}

// Wave-64 reductions on the VALU pipe via DPP (rocPRIM pattern): result in lane 63.
__device__ __forceinline__ float wave_red_max_f32(float v) {
#define DPPSTEP(ctrl)                                                                  \
    {                                                                                  \
        int _t = __builtin_amdgcn_update_dpp((int)0xFF800000, __float_as_int(v), ctrl, \
                                             0xf, 0xf, false);                         \
        v = fmaxf(v, __int_as_float(_t));                                              \
    }
    DPPSTEP(0x111) DPPSTEP(0x112) DPPSTEP(0x114) DPPSTEP(0x118) DPPSTEP(0x142) DPPSTEP(0x143)
#undef DPPSTEP
    return v;
}
__device__ __forceinline__ unsigned wave_red_min_u32(unsigned v) {
#define DPPSTEP(ctrl)                                                                   \
    {                                                                                   \
        unsigned _t = (unsigned)__builtin_amdgcn_update_dpp((int)0xFFFFFFFF, (int)v,    \
                                                            ctrl, 0xf, 0xf, false);     \
        v = v < _t ? v : _t;                                                            \
    }
    DPPSTEP(0x111) DPPSTEP(0x112) DPPSTEP(0x114) DPPSTEP(0x118) DPPSTEP(0x142) DPPSTEP(0x143)
#undef DPPSTEP
    return v;
}
__device__ __forceinline__ unsigned long long u64max(unsigned long long a, unsigned long long b) {
    return a > b ? a : b;
}
__device__ __forceinline__ unsigned u32min(unsigned a, unsigned b) { return a < b ? a : b; }

// ---------------- workspace layout (bytes); peak = 224,395,264 ------------------
static const size_t OFF_WBF   = 0;          // packed bf16 weights, 65536 elems (128 KB)
static const size_t OFF_STATS = 262144;     // 704 ch * 128 slots * 2 * 4B
static const size_t STATS_BYTES = 720896;
static const size_t OFF_AFF   = 1048576;    // per-layer scale/shift
static const size_t OFF_IDX0  = 2097152;    // 8*1024*32 ints
static const size_t OFF_IDX1  = 3145728;    // 8*1024*64 ints
static const size_t OFF_MX    = 5242880;    // 256*8192 fp32
static const size_t OFF_MN    = 13631488;
static const size_t OFF_Y0    = 22020096;   // bf16 X^T [NCOL][64]  (max 67 MB)
static const size_t OFF_Y1    = 90177536;   // bf16 X^T [NCOL][128] (max 134 MB)
static const size_t OFF_FEATT = 211812352;  // bf16 [8*8192][96] = 12.58 MB, overlaps Y1 tail
// (featTp last read in br1-L0; Y1 beyond 121.6 MB only written by br1-L1, which runs later)

// ---------------- fused pre-kernel: FPS (blocks 0..7) + feat transpose (8..1031)
//                  + weight pack (1032..1159), all concurrent on different CUs ----
__global__ __launch_bounds__(512) void fused_pre(
    const float* __restrict__ xyz, const float* __restrict__ feat,
    float* __restrict__ newxyz, unsigned short* __restrict__ ft,
    const float* __restrict__ w0, const float* __restrict__ w1, const float* __restrict__ w2,
    const float* __restrict__ w3, const float* __restrict__ w4, const float* __restrict__ w5,
    unsigned short* __restrict__ wb) {
    __shared__ union alignas(16) SM {
        struct {
            float ptsx[8200], ptsy[8200], ptsz[8200];
            float ldsM[16][3];
            float meanv[3];
            unsigned long long sKey[2][8];
            float cbuf[3072];  // selected centroids; written to global once at the end
        } f;
        float tile[64][65];
    } sm;
    const int tid = threadIdx.x;

    if (blockIdx.x >= 1032) {
        // ---- weight pack: w[M][K] f32 -> wb[Mp][Kp] bf16 (zero pad) ----
        int id = (int)(blockIdx.x - 1032) * 512 + tid;  // 0..65535
        const int psz[6] = {6144, 4096, 8192, 6144, 8192, 32768};
        const int Kp[6] = {96, 64, 64, 96, 64, 128};
        const int Ks[6] = {67, 64, 64, 67, 64, 128};
        const float* wp[6] = {w0, w1, w2, w3, w4, w5};
        int off = 0;
        for (int l = 0; l < 6; ++l) {
            if (id < off + psz[l]) {
                int e = id - off;
                int m = e / Kp[l], k = e - m * Kp[l];
                float v = (k < Ks[l]) ? wp[l][m * Ks[l] + k] : 0.f;
                wb[id] = f2bf(v);
                return;
            }
            off += psz[l];
        }
        return;
    }

    if (blockIdx.x >= 8) {
        // ---- featTp: [8][8192][96] bf16; c0..2 = xyz, c3..66 = feat, rest 0 ----
        int tb = (int)blockIdx.x - 8;  // 0..1023
        int b = tb >> 7;
        int j0 = (tb & 127) * 64;
#pragma unroll
        for (int i = 0; i < 8; ++i) {
            int e = i * 512 + tid;
            int c = e >> 6, j = e & 63;
            sm.tile[j][c] = feat[((size_t)b * 64 + c) * 8192 + j0 + j];
        }
        __syncthreads();
#pragma unroll
        for (int i = 0; i < 8; ++i) {
            int e = i * 512 + tid;
            int j = e >> 6, c = e & 63;
            ft[((size_t)(b * 8192 + j0 + j)) * 96 + 3 + c] = f2bf(sm.tile[j][c]);
        }
        if (tid < 64) {
            int j = tid;
            size_t base = ((size_t)(b * 8192 + j0 + j)) * 96;
            const float* xp = xyz + ((size_t)b * 8192 + j0 + j) * 3;
            ft[base + 0] = f2bf(xp[0]);
            ft[base + 1] = f2bf(xp[1]);
            ft[base + 2] = f2bf(xp[2]);
        } else if (tid < 128) {
            int j = tid - 64;
            size_t base = ((size_t)(b * 8192 + j0 + j)) * 96;
            for (int c = 67; c < 96; ++c) ft[base + c] = 0;
        }
        return;
    }

    // ---- FPS: 8 waves, 16 pts/thread as 8 float2 pairs ----
    const int b = blockIdx.x;
    const int t = tid;
    const int lane = t & 63, wv = t >> 6;
    const float* xb = xyz + (size_t)b * 8192 * 3;

    f32x2 px[8], py[8], pz[8], d[8];
#pragma unroll
    for (int k = 0; k < 8; ++k) {
        int q0 = t + 512 * (2 * k);
        int q1 = t + 512 * (2 * k + 1);
        px[k].x = xb[q0 * 3 + 0]; px[k].y = xb[q1 * 3 + 0];
        py[k].x = xb[q0 * 3 + 1]; py[k].y = xb[q1 * 3 + 1];
        pz[k].x = xb[q0 * 3 + 2]; pz[k].y = xb[q1 * 3 + 2];
        d[k].x = 1e10f; d[k].y = 1e10f;
        sm.f.ptsx[q0 + 1] = px[k].x; sm.f.ptsx[q1 + 1] = px[k].y;
        sm.f.ptsy[q0 + 1] = py[k].x; sm.f.ptsy[q1 + 1] = py[k].y;
        sm.f.ptsz[q0 + 1] = pz[k].x; sm.f.ptsz[q1 + 1] = pz[k].y;
    }
    // ---- mean: bit-identical replication of the v1 1024-partial tree ----
    float sxA = 0.f, syA = 0.f, szA = 0.f;
    float sxB = 0.f, syB = 0.f, szB = 0.f;
    int uA = (t + 1023) & 1023;
    int uB = (t + 511) & 1023;
#pragma unroll
    for (int j = 0; j < 8; ++j) {
        int ia = uA + 1024 * j;
        int ib = uB + 1024 * j;
        sxA += xb[ia * 3 + 0]; syA += xb[ia * 3 + 1]; szA += xb[ia * 3 + 2];
        sxB += xb[ib * 3 + 0]; syB += xb[ib * 3 + 1]; szB += xb[ib * 3 + 2];
    }
#pragma unroll
    for (int off = 32; off; off >>= 1) {
        sxA += __shfl_xor(sxA, off, 64);
        syA += __shfl_xor(syA, off, 64);
        szA += __shfl_xor(szA, off, 64);
        sxB += __shfl_xor(sxB, off, 64);
        syB += __shfl_xor(syB, off, 64);
        szB += __shfl_xor(szB, off, 64);
    }
    if (lane == 0) {
        sm.f.ldsM[wv][0] = sxA; sm.f.ldsM[wv][1] = syA; sm.f.ldsM[wv][2] = szA;
        sm.f.ldsM[wv + 8][0] = sxB; sm.f.ldsM[wv + 8][1] = syB; sm.f.ldsM[wv + 8][2] = szB;
    }
    __syncthreads();
    if (t < 3) {
        float s = 0.f;
        for (int w = 0; w < 16; ++w) s += sm.f.ldsM[w][t];
        sm.f.meanv[t] = s * (1.f / 8192.f);
    }
    __syncthreads();
    float cx = sm.f.meanv[0], cy = sm.f.meanv[1], cz = sm.f.meanv[2];
    const float mmx = cx, mmy = cy, mmz = cz;  // mean point (pts idx 0), owned by t0
    float dm = 1e10f;
    if (t == 0) { sm.f.ptsx[0] = cx; sm.f.ptsy[0] = cy; sm.f.ptsz[0] = cz; }
    __syncthreads();

    for (int it = 0; it < 1024; ++it) {
        if (t == 0) {
            sm.f.cbuf[it * 3 + 0] = cx;
            sm.f.cbuf[it * 3 + 1] = cy;
            sm.f.cbuf[it * 3 + 2] = cz;
        }
        f32x2 c0, c1, c2, vm2;
        c0.x = cx; c0.y = cx; c1.x = cy; c1.y = cy; c2.x = cz; c2.y = cz;
        vm2.x = -1e30f; vm2.y = -1e30f;
        {
#pragma clang fp contract(off)
#pragma unroll
            for (int k = 0; k < 8; ++k) {
                f32x2 dx = px[k] - c0;
                f32x2 dy = py[k] - c1;
                f32x2 dz = pz[k] - c2;
                f32x2 dd = (dx * dx + dy * dy) + dz * dz;
                f32x2 nd = __builtin_elementwise_min(d[k], dd);
                d[k] = nd;
                vm2 = __builtin_elementwise_max(vm2, nd);
            }
        }
        float vmax = fmaxf(vm2.x, vm2.y);
        if (t == 0) {
            float dx = __fsub_rn(mmx, cx);
            float dy = __fsub_rn(mmy, cy);
            float dz = __fsub_rn(mmz, cz);
            float dd = __fadd_rn(__fadd_rn(__fmul_rn(dx, dx), __fmul_rn(dy, dy)), __fmul_rn(dz, dz));
            dm = fminf(dm, dd);
            vmax = fmaxf(vmax, dm);
        }
        float wm = wave_red_max_f32(vmax);
        float bmaxw = __int_as_float(__builtin_amdgcn_readlane(__float_as_int(wm), 63));
        unsigned m2[8];
#pragma unroll
        for (int k = 0; k < 8; ++k) {
            unsigned i0 = (d[k].x == bmaxw) ? (unsigned)(t + 512 * (2 * k) + 1) : 0xFFFFFFFFu;
            unsigned i1 = (d[k].y == bmaxw) ? (unsigned)(t + 512 * (2 * k + 1) + 1) : 0xFFFFFFFFu;
            m2[k] = u32min(i0, i1);
        }
        unsigned n0 = u32min(m2[0], m2[1]), n1 = u32min(m2[2], m2[3]);
        unsigned n2 = u32min(m2[4], m2[5]), n3 = u32min(m2[6], m2[7]);
        unsigned mi = u32min(u32min(n0, n1), u32min(n2, n3));
        if (t == 0 && dm == bmaxw) mi = 0u;
        unsigned wmin = wave_red_min_u32(mi);
        unsigned miw = (unsigned)__builtin_amdgcn_readlane((int)wmin, 63);
        int par = it & 1;
        if (lane == 0)
            sm.f.sKey[par][wv] = ((unsigned long long)__float_as_uint(bmaxw) << 32) |
                                 (unsigned long long)(8192u - miw);
        __syncthreads();  // the ONLY barrier per iteration (parity-double-buffered slots)
        unsigned long long ka[8];
#pragma unroll
        for (int i = 0; i < 8; ++i) ka[i] = sm.f.sKey[par][i];  // same-address broadcasts
        unsigned long long p0 = u64max(ka[0], ka[1]), p1 = u64max(ka[2], ka[3]);
        unsigned long long p2 = u64max(ka[4], ka[5]), p3 = u64max(ka[6], ka[7]);
        unsigned long long kk = u64max(u64max(p0, p1), u64max(p2, p3));
        int far = 8192 - (int)(unsigned)(kk & 0xffffffffull);
        cx = sm.f.ptsx[far];  // uniform LDS broadcast
        cy = sm.f.ptsy[far];
        cz = sm.f.ptsz[far];
    }
    __syncthreads();
    float* ob = newxyz + (size_t)b * 3072;
#pragma unroll
    for (int i = 0; i < 6; ++i) ob[t + 512 * i] = sm.f.cbuf[t + 512 * i];
}

// ---------------- merged ball query: blocks 0..2047 br0 (K=32), 2048..4095 br1 --
__global__ void ball_query2(const float* __restrict__ xyz, const float* __restrict__ newxyz,
                            int* __restrict__ idx0, int* __restrict__ idx1) {
    int bid = blockIdx.x;
    int br = (bid >= 2048);
    int K = br ? 64 : 32;
    float r2 = br ? (0.8f * 0.8f) : (0.4f * 0.4f);
    int* idxout = br ? idx1 : idx0;
    int wid = (((bid & 2047) * 256) + threadIdx.x) >> 6;  // query id, 0..8191
    int lane = threadIdx.x & 63;
    int b = wid >> 10;
    const float* q = newxyz + (size_t)wid * 3;
    float qx = q[0], qy = q[1], qz = q[2];
    const float* xb = xyz + (size_t)b * 8192 * 3;
    int* out = idxout + (size_t)wid * K;
    int count = 0;
    int first = 0;
    for (int base = 0; base < 8192 && count < K; base += 64) {
        int j = base + lane;
        float dx = __fsub_rn(xb[j * 3 + 0], qx);
        float dy = __fsub_rn(xb[j * 3 + 1], qy);
        float dz = __fsub_rn(xb[j * 3 + 2], qz);
        float d2 = __fadd_rn(__fadd_rn(__fmul_rn(dx, dx), __fmul_rn(dy, dy)), __fmul_rn(dz, dz));
        bool in = d2 < r2;
        unsigned long long m = __ballot(in);
        if (count == 0 && m) first = base + __ffsll((long long)m) - 1;
        if (in) {
            int pos = count + __popcll(m & ((1ull << lane) - 1ull));
            if (pos < K) out[pos] = j;
        }
        count += __popcll(m);
    }
    if (count < K) {
        int fillv = (count > 0) ? first : 0;
        for (int p = count + lane; p < K; p += 64) out[p] = fillv;
    }
}

// ---------------- MFMA GEMM with conflict-free fragment-major LDS B-staging -----
// Bs holds 16B chunks in MFMA-fragment order: chunk id = (nt*KS+ks)*64 + lane,
// lane = quad*16 + n. Phase-1 writes (p = i*256+tid) and Phase-2 fragment reads
// (lane-sequential at fixed nt,ks) are both 16B lane-contiguous -> zero bank
// conflicts (was 8 lanes/bank-group with the padded row layout, 7.7M conflict
// cycles measured in R7). Arithmetic identical -> bit-identical outputs.
template <int Mp, int Kp, int IN_MODE, int OUT_MODE, int KSH>
__global__ __launch_bounds__(256) void gemm_mfma(
    const unsigned short* __restrict__ Wb, const unsigned short* __restrict__ Xin,
    const float* __restrict__ aff, const int* __restrict__ idx,
    const unsigned short* __restrict__ ftp, const float* __restrict__ newxyz,
    unsigned short* __restrict__ Yout, float* __restrict__ MX, float* __restrict__ MN,
    float* __restrict__ statS, float* __restrict__ statQ) {
    constexpr int MT = Mp / 64;
    constexpr int KS = Kp / 32;
    __shared__ unsigned short Bs[256 * KS * 8];  // 4 nt * KS ks * 64 lanes * 16B
    __shared__ float sAux[256];
    int* sAuxI = (int*)sAux;

    const int tid = threadIdx.x;
    const int w = tid >> 6;
    const int lane = tid & 63;
    const int n = lane & 15;
    const int quad = lane >> 4;
    const int rbase = w * (Mp / 4);
    const long col0 = (long)blockIdx.x * 64;

    short8 a[MT][KS];
#pragma unroll
    for (int mt = 0; mt < MT; ++mt)
#pragma unroll
        for (int ks = 0; ks < KS; ++ks)
            a[mt][ks] = *(const short8*)(Wb + (size_t)(rbase + mt * 16 + n) * Kp + ks * 32 + quad * 8);

    if constexpr (IN_MODE == 0) {
        if (tid < 64) {
            long colg = col0 + tid;
            sAuxI[tid] = idx[colg];
            long sk = colg >> KSH;
            sAux[64 + tid] = newxyz[sk * 3 + 0];
            sAux[128 + tid] = newxyz[sk * 3 + 1];
            sAux[192 + tid] = newxyz[sk * 3 + 2];
        }
    } else {
        if (tid < 2 * Kp) sAux[tid] = aff[tid];
    }
    __syncthreads();

    // ---- Phase 1: build B-tile in LDS, chunk p = i*256+tid (lane-sequential) ----
#pragma unroll
    for (int i = 0; i < KS; ++i) {
        int p = i * 256 + tid;
        int pl = p & 63;           // lane slot of the fragment
        int pn = pl & 15;          // n
        int pq = pl >> 4;          // quad
        int rest = p >> 6;         // nt*KS + ks
        int pks = rest % KS;
        int pnt = rest / KS;
        int col = pnt * 16 + pn;
        int kc = pks * 4 + pq;     // 16B chunk index along K
        short8 v;
        if constexpr (IN_MODE == 0) {
            const int bb = (int)(col0 >> (KSH + 10));
            int j = sAuxI[col];
            v = *(const short8*)(ftp + ((long)(bb * 8192 + j)) * 96 + kc * 8);
            if (kc == 0) {  // rel-xyz patch: channels 0..2
                v[0] = (short)f2bf(bf2f((unsigned short)v[0]) - sAux[64 + col]);
                v[1] = (short)f2bf(bf2f((unsigned short)v[1]) - sAux[128 + col]);
                v[2] = (short)f2bf(bf2f((unsigned short)v[2]) - sAux[192 + col]);
            }
        } else {
            short8 raw = *(const short8*)(Xin + (col0 + col) * (long)Kp + kc * 8);
#pragma unroll
            for (int e = 0; e < 8; ++e) {
                float xf = bf2f((unsigned short)raw[e]);
                xf = fmaxf(fmaf(xf, sAux[kc * 8 + e], sAux[Kp + kc * 8 + e]), 0.f);
                v[e] = (short)f2bf(xf);
            }
        }
        *(short8*)(&Bs[p * 8]) = v;
    }
    __syncthreads();

    // ---- Phase 2: MFMA from LDS fragments (lane-sequential ds_read_b128) ----
    f32x4 acc[MT][4];
#pragma unroll
    for (int mt = 0; mt < MT; ++mt)
#pragma unroll
        for (int nt = 0; nt < 4; ++nt)
#pragma unroll
            for (int r = 0; r < 4; ++r) acc[mt][nt][r] = 0.f;

#pragma unroll
    for (int ks = 0; ks < KS; ++ks) {
#pragma unroll
        for (int nt = 0; nt < 4; ++nt) {
            short8 bfr = *(const short8*)(&Bs[((nt * KS + ks) * 64 + lane) * 8]);
#pragma unroll
            for (int mt = 0; mt < MT; ++mt)
                acc[mt][nt] = __builtin_amdgcn_mfma_f32_16x16x32_bf16(a[mt][ks], bfr, acc[mt][nt], 0, 0, 0);
        }
    }

    // ---- stats: per-channel sum / sumsq ----
    const int slot = (int)(blockIdx.x & 127);
#pragma unroll
    for (int mt = 0; mt < MT; ++mt)
#pragma unroll
        for (int r = 0; r < 4; ++r) {
            float s = 0.f, q = 0.f;
#pragma unroll
            for (int nt = 0; nt < 4; ++nt) {
                float v = acc[mt][nt][r];
                s += v;
                q = fmaf(v, v, q);
            }
#pragma unroll
            for (int off = 1; off < 16; off <<= 1) {
                s += __shfl_xor(s, off, 16);
                q += __shfl_xor(q, off, 16);
            }
            if (n == 0) {
                int ch = rbase + mt * 16 + quad * 4 + r;
                atomicAdd(statS + (size_t)ch * 128 + slot, s);
                atomicAdd(statQ + (size_t)ch * 128 + slot, q);
            }
        }

    if constexpr (OUT_MODE == 0) {
#pragma unroll
        for (int mt = 0; mt < MT; ++mt)
#pragma unroll
            for (int nt = 0; nt < 4; ++nt) {
                long col = col0 + nt * 16 + n;
                unsigned p0 = f2bf(acc[mt][nt][0]) | ((unsigned)f2bf(acc[mt][nt][1]) << 16);
                unsigned p1 = f2bf(acc[mt][nt][2]) | ((unsigned)f2bf(acc[mt][nt][3]) << 16);
                uint2 st; st.x = p0; st.y = p1;
                *(uint2*)(Yout + col * Mp + rbase + mt * 16 + quad * 4) = st;
            }
    } else {
#pragma unroll
        for (int mt = 0; mt < MT; ++mt)
#pragma unroll
            for (int r = 0; r < 4; ++r) {
                if constexpr (KSH == 6) {
                    float mx = acc[mt][0][r], mn = acc[mt][0][r];
#pragma unroll
                    for (int nt = 1; nt < 4; ++nt) {
                        mx = fmaxf(mx, acc[mt][nt][r]);
                        mn = fminf(mn, acc[mt][nt][r]);
                    }
#pragma unroll
                    for (int off = 1; off < 16; off <<= 1) {
                        mx = fmaxf(mx, __shfl_xor(mx, off, 16));
                        mn = fminf(mn, __shfl_xor(mn, off, 16));
                    }
                    if (n == 0) {
                        int ch = rbase + mt * 16 + quad * 4 + r;
                        long g = col0 >> 6;
                        MX[(long)ch * 8192 + g] = mx;
                        MN[(long)ch * 8192 + g] = mn;
                    }
                } else {
#pragma unroll
                    for (int gh = 0; gh < 2; ++gh) {
                        float mx = fmaxf(acc[mt][2 * gh][r], acc[mt][2 * gh + 1][r]);
                        float mn = fminf(acc[mt][2 * gh][r], acc[mt][2 * gh + 1][r]);
#pragma unroll
                        for (int off = 1; off < 16; off <<= 1) {
                            mx = fmaxf(mx, __shfl_xor(mx, off, 16));
                            mn = fminf(mn, __shfl_xor(mn, off, 16));
                        }
                        if (n == 0) {
                            int ch = rbase + mt * 16 + quad * 4 + r;
                            long g = (col0 >> 5) + gh;
                            MX[(long)ch * 8192 + g] = mx;
                            MN[(long)ch * 8192 + g] = mn;
                        }
                    }
                }
            }
    }
}

// ---------------- finalize BN constants ----------------------------------------
__global__ void finalize_kernel(const float* __restrict__ sS, const float* __restrict__ sQ,
                                const float* __restrict__ g, const float* __restrict__ b,
                                float* __restrict__ aff, int C, float invCount) {
    int c = threadIdx.x + blockIdx.x * blockDim.x;
    if (c >= C) return;
    float s = 0.f, q = 0.f;
    for (int k = 0; k < 128; ++k) { s += sS[c * 128 + k]; q += sQ[c * 128 + k]; }
    float mean = s * invCount;
    float var = fmaxf(q * invCount - mean * mean, 0.f);
    float sc = g[c] / sqrtf(var + 1e-5f);
    float sh = b[c] - mean * sc;
    aff[c] = sc;
    aff[C + c] = sh;
}

// ---------------- final output -------------------------------------------------
__global__ void final_out_kernel(const float* __restrict__ MX, const float* __restrict__ MN,
                                 const float* __restrict__ aff, float* __restrict__ out1,
                                 int Cout, int cOff) {
    long i = (long)blockIdx.x * 256 + threadIdx.x;
    int c = (int)(i >> 13);
    int gidx = (int)(i & 8191);
    int b = gidx >> 10, s = gidx & 1023;
    float sc = aff[c], sh = aff[Cout + c];
    float v = fmaxf(fmaxf(sc * MX[i] + sh, sc * MN[i] + sh), 0.f);
    out1[((long)b * 384 + cOff + c) * 1024 + s] = v;
}

// ---------------- host ---------------------------------------------------------
extern "C" void kernel_launch(void* const* d_in, const int* in_sizes, int n_in,
                              void* d_out, int out_size, void* d_ws, size_t ws_size,
                              hipStream_t stream) {
    const float* xyz = (const float*)d_in[0];
    const float* feat = (const float*)d_in[1];
    const float *W[6], *G[6], *Bi[6];
    for (int l = 0; l < 6; ++l) {
        W[l] = (const float*)d_in[2 + l * 3];
        G[l] = (const float*)d_in[3 + l * 3];
        Bi[l] = (const float*)d_in[4 + l * 3];
    }
    char* ws = (char*)d_ws;
    float* out0 = (float*)d_out;
    float* out1 = (float*)d_out + 24576;

    unsigned short* wb = (unsigned short*)(ws + OFF_WBF);
    float* stats = (float*)(ws + OFF_STATS);
    float* affine = (float*)(ws + OFF_AFF);
    int* idx0 = (int*)(ws + OFF_IDX0);
    int* idx1 = (int*)(ws + OFF_IDX1);
    float* mx = (float*)(ws + OFF_MX);
    float* mn = (float*)(ws + OFF_MN);
    unsigned short* y0 = (unsigned short*)(ws + OFF_Y0);
    unsigned short* y1 = (unsigned short*)(ws + OFF_Y1);
    unsigned short* ftp = (unsigned short*)(ws + OFF_FEATT);

    hipMemsetAsync(stats, 0, STATS_BYTES, stream);
    fused_pre<<<1160, 512, 0, stream>>>(xyz, feat, out0, ftp, W[0], W[1], W[2], W[3], W[4],
                                        W[5], wb);
    ball_query2<<<4096, 256, 0, stream>>>(xyz, out0, idx0, idx1);

    const int wOff[6] = {0, 6144, 10240, 18432, 24576, 32768};
    int stOff[6], afOff[6];
    {
        const int Cs[6] = {64, 64, 128, 64, 128, 256};
        int so = 0, ao = 0;
        for (int l = 0; l < 6; ++l) {
            stOff[l] = so; so += Cs[l] * 256;
            afOff[l] = ao; ao += Cs[l] * 2;
        }
    }

    for (int br = 0; br < 2; ++br) {
        const int K = br ? 64 : 32;
        const long NCOL = 8L * 1024 * K;
        int* idx = br ? idx1 : idx0;
        const int l0 = br * 3, l1 = br * 3 + 1, l2 = br * 3 + 2;
        const int M2 = br ? 256 : 128;
        const float invCount = 1.f / (float)NCOL;
        const int nblk = (int)(NCOL / 64);

        if (br == 0) {
            gemm_mfma<64, 96, 0, 0, 5><<<nblk, 256, 0, stream>>>(
                wb + wOff[l0], nullptr, nullptr, idx, ftp, out0, y0, nullptr, nullptr,
                stats + stOff[l0], stats + stOff[l0] + 64 * 128);
            finalize_kernel<<<1, 256, 0, stream>>>(stats + stOff[l0], stats + stOff[l0] + 64 * 128,
                                                   G[l0], Bi[l0], affine + afOff[l0], 64, invCount);
            gemm_mfma<64, 64, 1, 0, 5><<<nblk, 256, 0, stream>>>(
                wb + wOff[l1], y0, affine + afOff[l0], nullptr, nullptr, nullptr, y1, nullptr,
                nullptr, stats + stOff[l1], stats + stOff[l1] + 64 * 128);
            finalize_kernel<<<1, 256, 0, stream>>>(stats + stOff[l1], stats + stOff[l1] + 64 * 128,
                                                   G[l1], Bi[l1], affine + afOff[l1], 64, invCount);
            gemm_mfma<128, 64, 1, 1, 5><<<nblk, 256, 0, stream>>>(
                wb + wOff[l2], y1, affine + afOff[l1], nullptr, nullptr, nullptr, nullptr, mx, mn,
                stats + stOff[l2], stats + stOff[l2] + 128 * 128);
            finalize_kernel<<<1, 256, 0, stream>>>(stats + stOff[l2], stats + stOff[l2] + 128 * 128,
                                                   G[l2], Bi[l2], affine + afOff[l2], 128, invCount);
        } else {
            gemm_mfma<64, 96, 0, 0, 6><<<nblk, 256, 0, stream>>>(
                wb + wOff[l0], nullptr, nullptr, idx, ftp, out0, y0, nullptr, nullptr,
                stats + stOff[l0], stats + stOff[l0] + 64 * 128);
            finalize_kernel<<<1, 256, 0, stream>>>(stats + stOff[l0], stats + stOff[l0] + 64 * 128,
                                                   G[l0], Bi[l0], affine + afOff[l0], 64, invCount);
            gemm_mfma<128, 64, 1, 0, 6><<<nblk, 256, 0, stream>>>(
                wb + wOff[l1], y0, affine + afOff[l0], nullptr, nullptr, nullptr, y1, nullptr,
                nullptr, stats + stOff[l1], stats + stOff[l1] + 128 * 128);
            finalize_kernel<<<1, 256, 0, stream>>>(stats + stOff[l1], stats + stOff[l1] + 128 * 128,
                                                   G[l1], Bi[l1], affine + afOff[l1], 128, invCount);
            gemm_mfma<256, 128, 1, 1, 6><<<nblk, 256, 0, stream>>>(
                wb + wOff[l2], y1, affine + afOff[l1], nullptr, nullptr, nullptr, nullptr, mx, mn,
                stats + stOff[l2], stats + stOff[l2] + 256 * 128);
            finalize_kernel<<<1, 256, 0, stream>>>(stats + stOff[l2], stats + stOff[l2] + 256 * 128,
                                                   G[l2], Bi[l2], affine + afOff[l2], 256, invCount);
        }

        final_out_kernel<<<(M2 * 8192) / 256, 256, 0, stream>>>(mx, mn, affine + afOff[l2], out1,
                                                                M2, br ? 128 : 0);
    }
}

// Round 9
// 1637.401 us; speedup vs baseline: 4.0275x; 1.0778x over previous
//
#include <hip/hip_runtime.h>
#include <hip/hip_bf16.h>
#include <cstdint>

// B=8, N=8192, S=1024, C=64
// branch0: r=0.4, K=32, layers 64x67, 64x64, 128x64
// branch1: r=0.8, K=64, layers 64x67, 128x64, 256x128

typedef __attribute__((ext_vector_type(8))) short short8;
typedef __attribute__((ext_vector_type(4))) float f32x4;
typedef __attribute__((ext_vector_type(2))) float f32x2;

__device__ __forceinline__ float bf2f(unsigned short u) {
    return __uint_as_float(((unsigned)u) << 16);
}
__device__ __forceinline__ unsigned short f2bf(float f) {
    unsigned u = __float_as_uint(f);
    return (unsigned short)((u + 0x7fffu + ((u >> 16) & 1u)) >> 16);  // RNE
}

// Wave-64 reductions on the VALU pipe via DPP (rocPRIM pattern): result in lane 63.
__device__ __forceinline__ float wave_red_max_f32(float v) {
#define DPPSTEP(ctrl)                                                                  \
    {                                                                                  \
        int _t = __builtin_amdgcn_update_dpp((int)0xFF800000, __float_as_int(v), ctrl, \
                                             0xf, 0xf, false);                         \
        v = fmaxf(v, __int_as_float(_t));                                              \
    }
    DPPSTEP(0x111) DPPSTEP(0x112) DPPSTEP(0x114) DPPSTEP(0x118) DPPSTEP(0x142) DPPSTEP(0x143)
#undef DPPSTEP
    return v;
}
__device__ __forceinline__ unsigned wave_red_min_u32(unsigned v) {
#define DPPSTEP(ctrl)                                                                   \
    {                                                                                   \
        unsigned _t = (unsigned)__builtin_amdgcn_update_dpp((int)0xFFFFFFFF, (int)v,    \
                                                            ctrl, 0xf, 0xf, false);     \
        v = v < _t ? v : _t;                                                            \
    }
    DPPSTEP(0x111) DPPSTEP(0x112) DPPSTEP(0x114) DPPSTEP(0x118) DPPSTEP(0x142) DPPSTEP(0x143)
#undef DPPSTEP
    return v;
}
__device__ __forceinline__ unsigned long long u64max(unsigned long long a, unsigned long long b) {
    return a > b ? a : b;
}
__device__ __forceinline__ unsigned u32min(unsigned a, unsigned b) { return a < b ? a : b; }

// ---------------- workspace layout (bytes); peak = 224,395,264 ------------------
static const size_t OFF_WBF   = 0;          // packed bf16 weights, 65536 elems (128 KB)
static const size_t OFF_STATS = 262144;     // 704 ch * 128 slots * 2 * 4B
static const size_t STATS_BYTES = 720896;
static const size_t OFF_AFF   = 1048576;    // per-layer scale/shift
static const size_t OFF_IDX0  = 2097152;    // 8*1024*32 ints
static const size_t OFF_IDX1  = 3145728;    // 8*1024*64 ints
static const size_t OFF_MX    = 5242880;    // 256*8192 fp32
static const size_t OFF_MN    = 13631488;
static const size_t OFF_Y0    = 22020096;   // bf16 X^T [NCOL][64]  (max 67 MB)
static const size_t OFF_Y1    = 90177536;   // bf16 X^T [NCOL][128] (max 134 MB)
static const size_t OFF_FEATT = 211812352;  // bf16 [8*8192][96] = 12.58 MB, overlaps Y1 tail
// (featTp last read in br1-L0; Y1 beyond 121.6 MB only written by br1-L1, which runs later)

// ---------------- fused pre-kernel (256 threads/block):
// FPS (blocks 0..7) + feat transpose (8..1031) + weight pack (1032..1287) ----
__global__ __launch_bounds__(256) void fused_pre(
    const float* __restrict__ xyz, const float* __restrict__ feat,
    float* __restrict__ newxyz, unsigned short* __restrict__ ft,
    const float* __restrict__ w0, const float* __restrict__ w1, const float* __restrict__ w2,
    const float* __restrict__ w3, const float* __restrict__ w4, const float* __restrict__ w5,
    unsigned short* __restrict__ wb) {
    __shared__ union alignas(16) SM {
        struct {
            float ptsx[8200], ptsy[8200], ptsz[8200];
            float ldsM[16][3];
            float meanv[3];
            unsigned long long sKey[2][4];
            float cbuf[3072];  // selected centroids; written to global once at the end
        } f;
        float tile[64][65];
    } sm;
    const int tid = threadIdx.x;

    if (blockIdx.x >= 1032) {
        // ---- weight pack: w[M][K] f32 -> wb[Mp][Kp] bf16 (zero pad) ----
        int id = (int)(blockIdx.x - 1032) * 256 + tid;  // 0..65535
        const int psz[6] = {6144, 4096, 8192, 6144, 8192, 32768};
        const int Kp[6] = {96, 64, 64, 96, 64, 128};
        const int Ks[6] = {67, 64, 64, 67, 64, 128};
        const float* wp[6] = {w0, w1, w2, w3, w4, w5};
        int off = 0;
        for (int l = 0; l < 6; ++l) {
            if (id < off + psz[l]) {
                int e = id - off;
                int m = e / Kp[l], k = e - m * Kp[l];
                float v = (k < Ks[l]) ? wp[l][m * Ks[l] + k] : 0.f;
                wb[id] = f2bf(v);
                return;
            }
            off += psz[l];
        }
        return;
    }

    if (blockIdx.x >= 8) {
        // ---- featTp: [8][8192][96] bf16; c0..2 = xyz, c3..66 = feat, rest 0 ----
        int tb = (int)blockIdx.x - 8;  // 0..1023
        int b = tb >> 7;
        int j0 = (tb & 127) * 64;
#pragma unroll
        for (int i = 0; i < 16; ++i) {
            int e = i * 256 + tid;
            int c = e >> 6, j = e & 63;
            sm.tile[j][c] = feat[((size_t)b * 64 + c) * 8192 + j0 + j];
        }
        __syncthreads();
#pragma unroll
        for (int i = 0; i < 16; ++i) {
            int e = i * 256 + tid;
            int j = e >> 6, c = e & 63;
            ft[((size_t)(b * 8192 + j0 + j)) * 96 + 3 + c] = f2bf(sm.tile[j][c]);
        }
        if (tid < 64) {
            int j = tid;
            size_t base = ((size_t)(b * 8192 + j0 + j)) * 96;
            const float* xp = xyz + ((size_t)b * 8192 + j0 + j) * 3;
            ft[base + 0] = f2bf(xp[0]);
            ft[base + 1] = f2bf(xp[1]);
            ft[base + 2] = f2bf(xp[2]);
        } else if (tid < 128) {
            int j = tid - 64;
            size_t base = ((size_t)(b * 8192 + j0 + j)) * 96;
            for (int c = 67; c < 96; ++c) ft[base + c] = 0;
        }
        return;
    }

    // ---- FPS: 4 waves (1/SIMD), 32 pts/thread as 16 float2 pairs ----
    // Per-SIMD issue = fixed point-work + (per-wave overhead x waves/SIMD); going
    // 8 waves -> 4 halves the duplicated reduction overhead per SIMD and shortens
    // the cross-wave combine (4 keys). Trajectory bit-identical to v8.
    const int b = blockIdx.x;
    const int t = tid;
    const int lane = t & 63, wv = t >> 6;  // wv 0..3
    const float* xb = xyz + (size_t)b * 8192 * 3;

    f32x2 px[16], py[16], pz[16], d[16];
#pragma unroll
    for (int k = 0; k < 16; ++k) {
        int q0 = t + 256 * (2 * k);
        int q1 = t + 256 * (2 * k + 1);
        px[k].x = xb[q0 * 3 + 0]; px[k].y = xb[q1 * 3 + 0];
        py[k].x = xb[q0 * 3 + 1]; py[k].y = xb[q1 * 3 + 1];
        pz[k].x = xb[q0 * 3 + 2]; pz[k].y = xb[q1 * 3 + 2];
        d[k].x = 1e10f; d[k].y = 1e10f;
        sm.f.ptsx[q0 + 1] = px[k].x; sm.f.ptsx[q1 + 1] = px[k].y;
        sm.f.ptsy[q0 + 1] = py[k].x; sm.f.ptsy[q1 + 1] = py[k].y;
        sm.f.ptsz[q0 + 1] = pz[k].x; sm.f.ptsz[q1 + 1] = pz[k].y;
    }
    // ---- mean: bit-identical replication of the v1 1024-partial tree ----
    // Role m (0..3) of thread t plays v1-thread t_old = t + 256m = 64*(wv+4m)+lane:
    // lane relationships inside each old wave preserved -> identical shfl trees.
    {
        float sx[4], sy[4], sz[4];
#pragma unroll
        for (int m = 0; m < 4; ++m) {
            int u = (t + 256 * m + 1023) & 1023;
            float ax = 0.f, ay = 0.f, az = 0.f;
#pragma unroll
            for (int jj = 0; jj < 8; ++jj) {
                int ia = u + 1024 * jj;
                ax += xb[ia * 3 + 0]; ay += xb[ia * 3 + 1]; az += xb[ia * 3 + 2];
            }
            sx[m] = ax; sy[m] = ay; sz[m] = az;
        }
#pragma unroll
        for (int off = 32; off; off >>= 1) {
#pragma unroll
            for (int m = 0; m < 4; ++m) {
                sx[m] += __shfl_xor(sx[m], off, 64);
                sy[m] += __shfl_xor(sy[m], off, 64);
                sz[m] += __shfl_xor(sz[m], off, 64);
            }
        }
        if (lane == 0) {
#pragma unroll
            for (int m = 0; m < 4; ++m) {
                sm.f.ldsM[wv + 4 * m][0] = sx[m];
                sm.f.ldsM[wv + 4 * m][1] = sy[m];
                sm.f.ldsM[wv + 4 * m][2] = sz[m];
            }
        }
    }
    __syncthreads();
    if (t < 3) {
        float s = 0.f;
        for (int w = 0; w < 16; ++w) s += sm.f.ldsM[w][t];
        sm.f.meanv[t] = s * (1.f / 8192.f);
    }
    __syncthreads();
    float cx = sm.f.meanv[0], cy = sm.f.meanv[1], cz = sm.f.meanv[2];
    const float mmx = cx, mmy = cy, mmz = cz;  // mean point (pts idx 0), owned by t0
    float dm = 1e10f;
    if (t == 0) { sm.f.ptsx[0] = cx; sm.f.ptsy[0] = cy; sm.f.ptsz[0] = cz; }
    __syncthreads();

    for (int it = 0; it < 1024; ++it) {
        if (t == 0) {
            sm.f.cbuf[it * 3 + 0] = cx;
            sm.f.cbuf[it * 3 + 1] = cy;
            sm.f.cbuf[it * 3 + 2] = cz;
        }
        f32x2 c0, c1, c2, vm2;
        c0.x = cx; c0.y = cx; c1.x = cy; c1.y = cy; c2.x = cz; c2.y = cz;
        vm2.x = -1e30f; vm2.y = -1e30f;
        {
#pragma clang fp contract(off)
#pragma unroll
            for (int k = 0; k < 16; ++k) {
                f32x2 dx = px[k] - c0;
                f32x2 dy = py[k] - c1;
                f32x2 dz = pz[k] - c2;
                f32x2 dd = (dx * dx + dy * dy) + dz * dz;
                f32x2 nd = __builtin_elementwise_min(d[k], dd);
                d[k] = nd;
                vm2 = __builtin_elementwise_max(vm2, nd);
            }
        }
        float vmax = fmaxf(vm2.x, vm2.y);
        if (t == 0) {
            float dx = __fsub_rn(mmx, cx);
            float dy = __fsub_rn(mmy, cy);
            float dz = __fsub_rn(mmz, cz);
            float dd = __fadd_rn(__fadd_rn(__fmul_rn(dx, dx), __fmul_rn(dy, dy)), __fmul_rn(dz, dz));
            dm = fminf(dm, dd);
            vmax = fmaxf(vmax, dm);
        }
        float wm = wave_red_max_f32(vmax);
        float bmaxw = __int_as_float(__builtin_amdgcn_readlane(__float_as_int(wm), 63));
        unsigned m2[16];
#pragma unroll
        for (int k = 0; k < 16; ++k) {
            unsigned i0 = (d[k].x == bmaxw) ? (unsigned)(t + 256 * (2 * k) + 1) : 0xFFFFFFFFu;
            unsigned i1 = (d[k].y == bmaxw) ? (unsigned)(t + 256 * (2 * k + 1) + 1) : 0xFFFFFFFFu;
            m2[k] = u32min(i0, i1);
        }
#pragma unroll
        for (int s = 8; s; s >>= 1)
#pragma unroll
            for (int k = 0; k < s; ++k) m2[k] = u32min(m2[k], m2[k + s]);
        unsigned mi = m2[0];
        if (t == 0 && dm == bmaxw) mi = 0u;
        unsigned wmin = wave_red_min_u32(mi);
        unsigned miw = (unsigned)__builtin_amdgcn_readlane((int)wmin, 63);
        int par = it & 1;
        if (lane == 0)
            sm.f.sKey[par][wv] = ((unsigned long long)__float_as_uint(bmaxw) << 32) |
                                 (unsigned long long)(8192u - miw);
        __syncthreads();  // the ONLY barrier per iteration (parity-double-buffered slots)
        unsigned long long ka[4];
#pragma unroll
        for (int i = 0; i < 4; ++i) ka[i] = sm.f.sKey[par][i];  // same-address broadcasts
        unsigned long long kk = u64max(u64max(ka[0], ka[1]), u64max(ka[2], ka[3]));
        int far = 8192 - (int)(unsigned)(kk & 0xffffffffull);
        cx = sm.f.ptsx[far];  // uniform LDS broadcast
        cy = sm.f.ptsy[far];
        cz = sm.f.ptsz[far];
    }
    __syncthreads();
    float* ob = newxyz + (size_t)b * 3072;
#pragma unroll
    for (int i = 0; i < 12; ++i) ob[t + 256 * i] = sm.f.cbuf[t + 256 * i];
}

// ---------------- merged ball query: blocks 0..2047 br0 (K=32), 2048..4095 br1 --
__global__ void ball_query2(const float* __restrict__ xyz, const float* __restrict__ newxyz,
                            int* __restrict__ idx0, int* __restrict__ idx1) {
    int bid = blockIdx.x;
    int br = (bid >= 2048);
    int K = br ? 64 : 32;
    float r2 = br ? (0.8f * 0.8f) : (0.4f * 0.4f);
    int* idxout = br ? idx1 : idx0;
    int wid = (((bid & 2047) * 256) + threadIdx.x) >> 6;  // query id, 0..8191
    int lane = threadIdx.x & 63;
    int b = wid >> 10;
    const float* q = newxyz + (size_t)wid * 3;
    float qx = q[0], qy = q[1], qz = q[2];
    const float* xb = xyz + (size_t)b * 8192 * 3;
    int* out = idxout + (size_t)wid * K;
    int count = 0;
    int first = 0;
    for (int base = 0; base < 8192 && count < K; base += 64) {
        int j = base + lane;
        float dx = __fsub_rn(xb[j * 3 + 0], qx);
        float dy = __fsub_rn(xb[j * 3 + 1], qy);
        float dz = __fsub_rn(xb[j * 3 + 2], qz);
        float d2 = __fadd_rn(__fadd_rn(__fmul_rn(dx, dx), __fmul_rn(dy, dy)), __fmul_rn(dz, dz));
        bool in = d2 < r2;
        unsigned long long m = __ballot(in);
        if (count == 0 && m) first = base + __ffsll((long long)m) - 1;
        if (in) {
            int pos = count + __popcll(m & ((1ull << lane) - 1ull));
            if (pos < K) out[pos] = j;
        }
        count += __popcll(m);
    }
    if (count < K) {
        int fillv = (count > 0) ? first : 0;
        for (int p = count + lane; p < K; p += 64) out[p] = fillv;
    }
}

// ---------------- MFMA GEMM, NT n-tiles (NT*16 cols) per block ------------------
// Fragment-major conflict-free LDS staging (R8-proven). NT=8 halves per-column
// epilogue/staging overhead for the MT<=2 layers; big layer stays NT=4 (VGPR).
template <int Mp, int Kp, int IN_MODE, int OUT_MODE, int KSH, int NT>
__global__ __launch_bounds__(256) void gemm_mfma(
    const unsigned short* __restrict__ Wb, const unsigned short* __restrict__ Xin,
    const float* __restrict__ aff, const int* __restrict__ idx,
    const unsigned short* __restrict__ ftp, const float* __restrict__ newxyz,
    unsigned short* __restrict__ Yout, float* __restrict__ MX, float* __restrict__ MN,
    float* __restrict__ statS, float* __restrict__ statQ) {
    constexpr int MT = Mp / 64;
    constexpr int KS = Kp / 32;
    constexpr int NC = NT * 16;              // cols per block
    constexpr int NCHUNK = NT * KS * 64;     // 16B chunks in Bs
    __shared__ unsigned short Bs[NCHUNK * 8];
    __shared__ float sAux[NT * 64];          // IN0: idx + 3q per col; IN1: 2*Kp affine
    int* sAuxI = (int*)sAux;

    const int tid = threadIdx.x;
    const int w = tid >> 6;
    const int lane = tid & 63;
    const int n = lane & 15;
    const int quad = lane >> 4;
    const int rbase = w * (Mp / 4);
    const long col0 = (long)blockIdx.x * NC;

    short8 a[MT][KS];
#pragma unroll
    for (int mt = 0; mt < MT; ++mt)
#pragma unroll
        for (int ks = 0; ks < KS; ++ks)
            a[mt][ks] = *(const short8*)(Wb + (size_t)(rbase + mt * 16 + n) * Kp + ks * 32 + quad * 8);

    if constexpr (IN_MODE == 0) {
        if (tid < NC) {
            long colg = col0 + tid;
            sAuxI[tid] = idx[colg];
            long sk = colg >> KSH;
            sAux[NC + tid] = newxyz[sk * 3 + 0];
            sAux[2 * NC + tid] = newxyz[sk * 3 + 1];
            sAux[3 * NC + tid] = newxyz[sk * 3 + 2];
        }
    } else {
        if (tid < 2 * Kp) sAux[tid] = aff[tid];
    }
    __syncthreads();

    // ---- Phase 1: build B-tile in LDS, chunk p = i*256+tid (lane-sequential) ----
#pragma unroll
    for (int i = 0; i < NCHUNK / 256; ++i) {
        int p = i * 256 + tid;
        int pl = p & 63;
        int pn = pl & 15;
        int pq = pl >> 4;
        int rest = p >> 6;  // pnt*KS + pks
        int pks = rest % KS;
        int pnt = rest / KS;
        int col = pnt * 16 + pn;
        int kc = pks * 4 + pq;  // 16B chunk index along K
        short8 v;
        if constexpr (IN_MODE == 0) {
            const int bb = (int)(col0 >> (KSH + 10));
            int j = sAuxI[col];
            v = *(const short8*)(ftp + ((long)(bb * 8192 + j)) * 96 + kc * 8);
            if (kc == 0) {  // rel-xyz patch: channels 0..2
                v[0] = (short)f2bf(bf2f((unsigned short)v[0]) - sAux[NC + col]);
                v[1] = (short)f2bf(bf2f((unsigned short)v[1]) - sAux[2 * NC + col]);
                v[2] = (short)f2bf(bf2f((unsigned short)v[2]) - sAux[3 * NC + col]);
            }
        } else {
            short8 raw = *(const short8*)(Xin + (col0 + col) * (long)Kp + kc * 8);
#pragma unroll
            for (int e = 0; e < 8; ++e) {
                float xf = bf2f((unsigned short)raw[e]);
                xf = fmaxf(fmaf(xf, sAux[kc * 8 + e], sAux[Kp + kc * 8 + e]), 0.f);
                v[e] = (short)f2bf(xf);
            }
        }
        *(short8*)(&Bs[p * 8]) = v;
    }
    __syncthreads();

    // ---- Phase 2: MFMA from LDS fragments (lane-sequential ds_read_b128) ----
    f32x4 acc[MT][NT];
#pragma unroll
    for (int mt = 0; mt < MT; ++mt)
#pragma unroll
        for (int nt = 0; nt < NT; ++nt)
#pragma unroll
            for (int r = 0; r < 4; ++r) acc[mt][nt][r] = 0.f;

#pragma unroll
    for (int ks = 0; ks < KS; ++ks) {
#pragma unroll
        for (int nt = 0; nt < NT; ++nt) {
            short8 bfr = *(const short8*)(&Bs[((nt * KS + ks) * 64 + lane) * 8]);
#pragma unroll
            for (int mt = 0; mt < MT; ++mt)
                acc[mt][nt] = __builtin_amdgcn_mfma_f32_16x16x32_bf16(a[mt][ks], bfr, acc[mt][nt], 0, 0, 0);
        }
    }

    // ---- stats: per-channel sum / sumsq ----
    const int slot = (int)(blockIdx.x & 127);
#pragma unroll
    for (int mt = 0; mt < MT; ++mt)
#pragma unroll
        for (int r = 0; r < 4; ++r) {
            float s = 0.f, q = 0.f;
#pragma unroll
            for (int nt = 0; nt < NT; ++nt) {
                float v = acc[mt][nt][r];
                s += v;
                q = fmaf(v, v, q);
            }
#pragma unroll
            for (int off = 1; off < 16; off <<= 1) {
                s += __shfl_xor(s, off, 16);
                q += __shfl_xor(q, off, 16);
            }
            if (n == 0) {
                int ch = rbase + mt * 16 + quad * 4 + r;
                atomicAdd(statS + (size_t)ch * 128 + slot, s);
                atomicAdd(statQ + (size_t)ch * 128 + slot, q);
            }
        }

    if constexpr (OUT_MODE == 0) {
#pragma unroll
        for (int mt = 0; mt < MT; ++mt)
#pragma unroll
            for (int nt = 0; nt < NT; ++nt) {
                long col = col0 + nt * 16 + n;
                unsigned p0 = f2bf(acc[mt][nt][0]) | ((unsigned)f2bf(acc[mt][nt][1]) << 16);
                unsigned p1 = f2bf(acc[mt][nt][2]) | ((unsigned)f2bf(acc[mt][nt][3]) << 16);
                uint2 st; st.x = p0; st.y = p1;
                *(uint2*)(Yout + col * Mp + rbase + mt * 16 + quad * 4) = st;
            }
    } else {
        constexpr int GRP = (1 << KSH) / 16;  // n-tiles per K-sample group (2 or 4)
        constexpr int NG = NT / GRP;          // groups per block
#pragma unroll
        for (int mt = 0; mt < MT; ++mt)
#pragma unroll
            for (int r = 0; r < 4; ++r) {
#pragma unroll
                for (int gh = 0; gh < NG; ++gh) {
                    float mx = acc[mt][GRP * gh][r], mn = acc[mt][GRP * gh][r];
#pragma unroll
                    for (int e = 1; e < GRP; ++e) {
                        mx = fmaxf(mx, acc[mt][GRP * gh + e][r]);
                        mn = fminf(mn, acc[mt][GRP * gh + e][r]);
                    }
#pragma unroll
                    for (int off = 1; off < 16; off <<= 1) {
                        mx = fmaxf(mx, __shfl_xor(mx, off, 16));
                        mn = fminf(mn, __shfl_xor(mn, off, 16));
                    }
                    if (n == 0) {
                        int ch = rbase + mt * 16 + quad * 4 + r;
                        long g = (col0 >> KSH) + gh;
                        MX[(long)ch * 8192 + g] = mx;
                        MN[(long)ch * 8192 + g] = mn;
                    }
                }
            }
    }
}

// ---------------- finalize BN constants ----------------------------------------
__global__ void finalize_kernel(const float* __restrict__ sS, const float* __restrict__ sQ,
                                const float* __restrict__ g, const float* __restrict__ b,
                                float* __restrict__ aff, int C, float invCount) {
    int c = threadIdx.x + blockIdx.x * blockDim.x;
    if (c >= C) return;
    float s = 0.f, q = 0.f;
    for (int k = 0; k < 128; ++k) { s += sS[c * 128 + k]; q += sQ[c * 128 + k]; }
    float mean = s * invCount;
    float var = fmaxf(q * invCount - mean * mean, 0.f);
    float sc = g[c] / sqrtf(var + 1e-5f);
    float sh = b[c] - mean * sc;
    aff[c] = sc;
    aff[C + c] = sh;
}

// ---------------- final output -------------------------------------------------
__global__ void final_out_kernel(const float* __restrict__ MX, const float* __restrict__ MN,
                                 const float* __restrict__ aff, float* __restrict__ out1,
                                 int Cout, int cOff) {
    long i = (long)blockIdx.x * 256 + threadIdx.x;
    int c = (int)(i >> 13);
    int gidx = (int)(i & 8191);
    int b = gidx >> 10, s = gidx & 1023;
    float sc = aff[c], sh = aff[Cout + c];
    float v = fmaxf(fmaxf(sc * MX[i] + sh, sc * MN[i] + sh), 0.f);
    out1[((long)b * 384 + cOff + c) * 1024 + s] = v;
}

// ---------------- host ---------------------------------------------------------
extern "C" void kernel_launch(void* const* d_in, const int* in_sizes, int n_in,
                              void* d_out, int out_size, void* d_ws, size_t ws_size,
                              hipStream_t stream) {
    const float* xyz = (const float*)d_in[0];
    const float* feat = (const float*)d_in[1];
    const float *W[6], *G[6], *Bi[6];
    for (int l = 0; l < 6; ++l) {
        W[l] = (const float*)d_in[2 + l * 3];
        G[l] = (const float*)d_in[3 + l * 3];
        Bi[l] = (const float*)d_in[4 + l * 3];
    }
    char* ws = (char*)d_ws;
    float* out0 = (float*)d_out;
    float* out1 = (float*)d_out + 24576;

    unsigned short* wb = (unsigned short*)(ws + OFF_WBF);
    float* stats = (float*)(ws + OFF_STATS);
    float* affine = (float*)(ws + OFF_AFF);
    int* idx0 = (int*)(ws + OFF_IDX0);
    int* idx1 = (int*)(ws + OFF_IDX1);
    float* mx = (float*)(ws + OFF_MX);
    float* mn = (float*)(ws + OFF_MN);
    unsigned short* y0 = (unsigned short*)(ws + OFF_Y0);
    unsigned short* y1 = (unsigned short*)(ws + OFF_Y1);
    unsigned short* ftp = (unsigned short*)(ws + OFF_FEATT);

    hipMemsetAsync(stats, 0, STATS_BYTES, stream);
    fused_pre<<<1288, 256, 0, stream>>>(xyz, feat, out0, ftp, W[0], W[1], W[2], W[3], W[4],
                                        W[5], wb);
    ball_query2<<<4096, 256, 0, stream>>>(xyz, out0, idx0, idx1);

    const int wOff[6] = {0, 6144, 10240, 18432, 24576, 32768};
    int stOff[6], afOff[6];
    {
        const int Cs[6] = {64, 64, 128, 64, 128, 256};
        int so = 0, ao = 0;
        for (int l = 0; l < 6; ++l) {
            stOff[l] = so; so += Cs[l] * 256;
            afOff[l] = ao; ao += Cs[l] * 2;
        }
    }

    for (int br = 0; br < 2; ++br) {
        const int K = br ? 64 : 32;
        const long NCOL = 8L * 1024 * K;
        int* idx = br ? idx1 : idx0;
        const int l0 = br * 3, l1 = br * 3 + 1, l2 = br * 3 + 2;
        const int M2 = br ? 256 : 128;
        const float invCount = 1.f / (float)NCOL;
        const int nblk128 = (int)(NCOL / 128);
        const int nblk64 = (int)(NCOL / 64);

        if (br == 0) {
            gemm_mfma<64, 96, 0, 0, 5, 8><<<nblk128, 256, 0, stream>>>(
                wb + wOff[l0], nullptr, nullptr, idx, ftp, out0, y0, nullptr, nullptr,
                stats + stOff[l0], stats + stOff[l0] + 64 * 128);
            finalize_kernel<<<1, 256, 0, stream>>>(stats + stOff[l0], stats + stOff[l0] + 64 * 128,
                                                   G[l0], Bi[l0], affine + afOff[l0], 64, invCount);
            gemm_mfma<64, 64, 1, 0, 5, 8><<<nblk128, 256, 0, stream>>>(
                wb + wOff[l1], y0, affine + afOff[l0], nullptr, nullptr, nullptr, y1, nullptr,
                nullptr, stats + stOff[l1], stats + stOff[l1] + 64 * 128);
            finalize_kernel<<<1, 256, 0, stream>>>(stats + stOff[l1], stats + stOff[l1] + 64 * 128,
                                                   G[l1], Bi[l1], affine + afOff[l1], 64, invCount);
            gemm_mfma<128, 64, 1, 1, 5, 8><<<nblk128, 256, 0, stream>>>(
                wb + wOff[l2], y1, affine + afOff[l1], nullptr, nullptr, nullptr, nullptr, mx, mn,
                stats + stOff[l2], stats + stOff[l2] + 128 * 128);
            finalize_kernel<<<1, 256, 0, stream>>>(stats + stOff[l2], stats + stOff[l2] + 128 * 128,
                                                   G[l2], Bi[l2], affine + afOff[l2], 128, invCount);
        } else {
            gemm_mfma<64, 96, 0, 0, 6, 8><<<nblk128, 256, 0, stream>>>(
                wb + wOff[l0], nullptr, nullptr, idx, ftp, out0, y0, nullptr, nullptr,
                stats + stOff[l0], stats + stOff[l0] + 64 * 128);
            finalize_kernel<<<1, 256, 0, stream>>>(stats + stOff[l0], stats + stOff[l0] + 64 * 128,
                                                   G[l0], Bi[l0], affine + afOff[l0], 64, invCount);
            gemm_mfma<128, 64, 1, 0, 6, 8><<<nblk128, 256, 0, stream>>>(
                wb + wOff[l1], y0, affine + afOff[l0], nullptr, nullptr, nullptr, y1, nullptr,
                nullptr, stats + stOff[l1], stats + stOff[l1] + 128 * 128);
            finalize_kernel<<<1, 256, 0, stream>>>(stats + stOff[l1], stats + stOff[l1] + 128 * 128,
                                                   G[l1], Bi[l1], affine + afOff[l1], 128, invCount);
            gemm_mfma<256, 128, 1, 1, 6, 4><<<nblk64, 256, 0, stream>>>(
                wb + wOff[l2], y1, affine + afOff[l1], nullptr, nullptr, nullptr, nullptr, mx, mn,
                stats + stOff[l2], stats + stOff[l2] + 256 * 128);
            finalize_kernel<<<1, 256, 0, stream>>>(stats + stOff[l2], stats + stOff[l2] + 256 * 128,
                                                   G[l2], Bi[l2], affine + afOff[l2], 256, invCount);
        }

        final_out_kernel<<<(M2 * 8192) / 256, 256, 0, stream>>>(mx, mn, affine + afOff[l2], out1,
                                                                M2, br ? 128 : 0);
    }
}

// Round 10
// 1635.423 us; speedup vs baseline: 4.0323x; 1.0012x over previous
//
#include <hip/hip_runtime.h>
#include <hip/hip_bf16.h>
#include <cstdint>

// B=8, N=8192, S=1024, C=64
// branch0: r=0.4, K=32, layers 64x67, 64x64, 128x64
// branch1: r=0.8, K=64, layers 64x67, 128x64, 256x128

typedef __attribute__((ext_vector_type(8))) short short8;
typedef __attribute__((ext_vector_type(4))) float f32x4;
typedef __attribute__((ext_vector_type(2))) float f32x2;

__device__ __forceinline__ float bf2f(unsigned short u) {
    return __uint_as_float(((unsigned)u) << 16);
}
__device__ __forceinline__ unsigned short f2bf(float f) {
    unsigned u = __float_as_uint(f);
    return (unsigned short)((u + 0x7fffu + ((u >> 16) & 1u)) >> 16);  // RNE
}

// Wave-64 reductions on the VALU pipe via DPP (rocPRIM pattern): result in lane 63.
__device__ __forceinline__ float wave_red_max_f32(float v) {
#define DPPSTEP(ctrl)                                                                  \
    {                                                                                  \
        int _t = __builtin_amdgcn_update_dpp((int)0xFF800000, __float_as_int(v), ctrl, \
                                             0xf, 0xf, false);                         \
        v = fmaxf(v, __int_as_float(_t));                                              \
    }
    DPPSTEP(0x111) DPPSTEP(0x112) DPPSTEP(0x114) DPPSTEP(0x118) DPPSTEP(0x142) DPPSTEP(0x143)
#undef DPPSTEP
    return v;
}
__device__ __forceinline__ unsigned wave_red_min_u32(unsigned v) {
#define DPPSTEP(ctrl)                                                                   \
    {                                                                                   \
        unsigned _t = (unsigned)__builtin_amdgcn_update_dpp((int)0xFFFFFFFF, (int)v,    \
                                                            ctrl, 0xf, 0xf, false);     \
        v = v < _t ? v : _t;                                                            \
    }
    DPPSTEP(0x111) DPPSTEP(0x112) DPPSTEP(0x114) DPPSTEP(0x118) DPPSTEP(0x142) DPPSTEP(0x143)
#undef DPPSTEP
    return v;
}
__device__ __forceinline__ unsigned long long u64max(unsigned long long a, unsigned long long b) {
    return a > b ? a : b;
}
__device__ __forceinline__ unsigned u32min(unsigned a, unsigned b) { return a < b ? a : b; }

// ---------------- workspace layout (bytes); peak = 224,395,264 ------------------
static const size_t OFF_WBF   = 0;          // packed bf16 weights, 65536 elems (128 KB)
static const size_t OFF_STATS = 262144;     // 704 ch * 128 slots * 2 * 4B
static const size_t STATS_BYTES = 720896;
static const size_t OFF_AFF   = 1048576;    // per-layer scale/shift
static const size_t OFF_IDX0  = 2097152;    // 8*1024*32 ints
static const size_t OFF_IDX1  = 3145728;    // 8*1024*64 ints
static const size_t OFF_MX    = 5242880;    // 256*8192 fp32
static const size_t OFF_MN    = 13631488;
static const size_t OFF_Y0    = 22020096;   // bf16 X^T [NCOL][64]  (max 67 MB)
static const size_t OFF_Y1    = 90177536;   // bf16 X^T [NCOL][128] (max 134 MB)
static const size_t OFF_FEATT = 211812352;  // bf16 [8*8192][96] = 12.58 MB, overlaps Y1 tail
// (featTp last read in br1-L0; Y1 beyond 121.6 MB only written by br1-L1, which runs later)

// ---------------- fused pre-kernel (256 threads/block):
// FPS (blocks 0..7) + feat transpose (8..1031) + weight pack (1032..1287) ----
__global__ __launch_bounds__(256) void fused_pre(
    const float* __restrict__ xyz, const float* __restrict__ feat,
    float* __restrict__ newxyz, unsigned short* __restrict__ ft,
    const float* __restrict__ w0, const float* __restrict__ w1, const float* __restrict__ w2,
    const float* __restrict__ w3, const float* __restrict__ w4, const float* __restrict__ w5,
    unsigned short* __restrict__ wb) {
    __shared__ union alignas(16) SM {
        struct {
            float ptsx[8200], ptsy[8200], ptsz[8200];
            float ldsM[16][3];
            float meanv[3];
            unsigned long long sKey[2][4];
            float cbuf[3072];  // selected centroids; written to global once at the end
        } f;
        float tile[64][65];
    } sm;
    const int tid = threadIdx.x;

    if (blockIdx.x >= 1032) {
        // ---- weight pack: w[M][K] f32 -> wb[Mp][Kp] bf16 (zero pad) ----
        int id = (int)(blockIdx.x - 1032) * 256 + tid;  // 0..65535
        const int psz[6] = {6144, 4096, 8192, 6144, 8192, 32768};
        const int Kp[6] = {96, 64, 64, 96, 64, 128};
        const int Ks[6] = {67, 64, 64, 67, 64, 128};
        const float* wp[6] = {w0, w1, w2, w3, w4, w5};
        int off = 0;
        for (int l = 0; l < 6; ++l) {
            if (id < off + psz[l]) {
                int e = id - off;
                int m = e / Kp[l], k = e - m * Kp[l];
                float v = (k < Ks[l]) ? wp[l][m * Ks[l] + k] : 0.f;
                wb[id] = f2bf(v);
                return;
            }
            off += psz[l];
        }
        return;
    }

    if (blockIdx.x >= 8) {
        // ---- featTp: [8][8192][96] bf16; c0..2 = xyz, c3..66 = feat, rest 0 ----
        int tb = (int)blockIdx.x - 8;  // 0..1023
        int b = tb >> 7;
        int j0 = (tb & 127) * 64;
#pragma unroll
        for (int i = 0; i < 16; ++i) {
            int e = i * 256 + tid;
            int c = e >> 6, j = e & 63;
            sm.tile[j][c] = feat[((size_t)b * 64 + c) * 8192 + j0 + j];
        }
        __syncthreads();
#pragma unroll
        for (int i = 0; i < 16; ++i) {
            int e = i * 256 + tid;
            int j = e >> 6, c = e & 63;
            ft[((size_t)(b * 8192 + j0 + j)) * 96 + 3 + c] = f2bf(sm.tile[j][c]);
        }
        if (tid < 64) {
            int j = tid;
            size_t base = ((size_t)(b * 8192 + j0 + j)) * 96;
            const float* xp = xyz + ((size_t)b * 8192 + j0 + j) * 3;
            ft[base + 0] = f2bf(xp[0]);
            ft[base + 1] = f2bf(xp[1]);
            ft[base + 2] = f2bf(xp[2]);
        } else if (tid < 128) {
            int j = tid - 64;
            size_t base = ((size_t)(b * 8192 + j0 + j)) * 96;
            for (int c = 67; c < 96; ++c) ft[base + c] = 0;
        }
        return;
    }

    // ---- FPS: 4 waves (1/SIMD), 32 pts/thread as 16 float2 pairs (R9-proven) ----
    const int b = blockIdx.x;
    const int t = tid;
    const int lane = t & 63, wv = t >> 6;  // wv 0..3
    const float* xb = xyz + (size_t)b * 8192 * 3;

    f32x2 px[16], py[16], pz[16], d[16];
#pragma unroll
    for (int k = 0; k < 16; ++k) {
        int q0 = t + 256 * (2 * k);
        int q1 = t + 256 * (2 * k + 1);
        px[k].x = xb[q0 * 3 + 0]; px[k].y = xb[q1 * 3 + 0];
        py[k].x = xb[q0 * 3 + 1]; py[k].y = xb[q1 * 3 + 1];
        pz[k].x = xb[q0 * 3 + 2]; pz[k].y = xb[q1 * 3 + 2];
        d[k].x = 1e10f; d[k].y = 1e10f;
        sm.f.ptsx[q0 + 1] = px[k].x; sm.f.ptsx[q1 + 1] = px[k].y;
        sm.f.ptsy[q0 + 1] = py[k].x; sm.f.ptsy[q1 + 1] = py[k].y;
        sm.f.ptsz[q0 + 1] = pz[k].x; sm.f.ptsz[q1 + 1] = pz[k].y;
    }
    // ---- mean: bit-identical replication of the v1 1024-partial tree ----
    {
        float sx[4], sy[4], sz[4];
#pragma unroll
        for (int m = 0; m < 4; ++m) {
            int u = (t + 256 * m + 1023) & 1023;
            float ax = 0.f, ay = 0.f, az = 0.f;
#pragma unroll
            for (int jj = 0; jj < 8; ++jj) {
                int ia = u + 1024 * jj;
                ax += xb[ia * 3 + 0]; ay += xb[ia * 3 + 1]; az += xb[ia * 3 + 2];
            }
            sx[m] = ax; sy[m] = ay; sz[m] = az;
        }
#pragma unroll
        for (int off = 32; off; off >>= 1) {
#pragma unroll
            for (int m = 0; m < 4; ++m) {
                sx[m] += __shfl_xor(sx[m], off, 64);
                sy[m] += __shfl_xor(sy[m], off, 64);
                sz[m] += __shfl_xor(sz[m], off, 64);
            }
        }
        if (lane == 0) {
#pragma unroll
            for (int m = 0; m < 4; ++m) {
                sm.f.ldsM[wv + 4 * m][0] = sx[m];
                sm.f.ldsM[wv + 4 * m][1] = sy[m];
                sm.f.ldsM[wv + 4 * m][2] = sz[m];
            }
        }
    }
    __syncthreads();
    if (t < 3) {
        float s = 0.f;
        for (int w = 0; w < 16; ++w) s += sm.f.ldsM[w][t];
        sm.f.meanv[t] = s * (1.f / 8192.f);
    }
    __syncthreads();
    float cx = sm.f.meanv[0], cy = sm.f.meanv[1], cz = sm.f.meanv[2];
    const float mmx = cx, mmy = cy, mmz = cz;  // mean point (pts idx 0), owned by t0
    float dm = 1e10f;
    if (t == 0) { sm.f.ptsx[0] = cx; sm.f.ptsy[0] = cy; sm.f.ptsz[0] = cz; }
    __syncthreads();

    for (int it = 0; it < 1024; ++it) {
        if (t == 0) {
            sm.f.cbuf[it * 3 + 0] = cx;
            sm.f.cbuf[it * 3 + 1] = cy;
            sm.f.cbuf[it * 3 + 2] = cz;
        }
        f32x2 c0, c1, c2, vm2;
        c0.x = cx; c0.y = cx; c1.x = cy; c1.y = cy; c2.x = cz; c2.y = cz;
        vm2.x = -1e30f; vm2.y = -1e30f;
        {
#pragma clang fp contract(off)
#pragma unroll
            for (int k = 0; k < 16; ++k) {
                f32x2 dx = px[k] - c0;
                f32x2 dy = py[k] - c1;
                f32x2 dz = pz[k] - c2;
                f32x2 dd = (dx * dx + dy * dy) + dz * dz;
                f32x2 nd = __builtin_elementwise_min(d[k], dd);
                d[k] = nd;
                vm2 = __builtin_elementwise_max(vm2, nd);
            }
        }
        float vmax = fmaxf(vm2.x, vm2.y);
        if (t == 0) {
            float dx = __fsub_rn(mmx, cx);
            float dy = __fsub_rn(mmy, cy);
            float dz = __fsub_rn(mmz, cz);
            float dd = __fadd_rn(__fadd_rn(__fmul_rn(dx, dx), __fmul_rn(dy, dy)), __fmul_rn(dz, dz));
            dm = fminf(dm, dd);
            vmax = fmaxf(vmax, dm);
        }
        float wm = wave_red_max_f32(vmax);
        float bmaxw = __int_as_float(__builtin_amdgcn_readlane(__float_as_int(wm), 63));
        unsigned m2[16];
#pragma unroll
        for (int k = 0; k < 16; ++k) {
            unsigned i0 = (d[k].x == bmaxw) ? (unsigned)(t + 256 * (2 * k) + 1) : 0xFFFFFFFFu;
            unsigned i1 = (d[k].y == bmaxw) ? (unsigned)(t + 256 * (2 * k + 1) + 1) : 0xFFFFFFFFu;
            m2[k] = u32min(i0, i1);
        }
#pragma unroll
        for (int s = 8; s; s >>= 1)
#pragma unroll
            for (int k = 0; k < s; ++k) m2[k] = u32min(m2[k], m2[k + s]);
        unsigned mi = m2[0];
        if (t == 0 && dm == bmaxw) mi = 0u;
        unsigned wmin = wave_red_min_u32(mi);
        unsigned miw = (unsigned)__builtin_amdgcn_readlane((int)wmin, 63);
        int par = it & 1;
        if (lane == 0)
            sm.f.sKey[par][wv] = ((unsigned long long)__float_as_uint(bmaxw) << 32) |
                                 (unsigned long long)(8192u - miw);
        __syncthreads();  // the ONLY barrier per iteration (parity-double-buffered slots)
        unsigned long long ka[4];
#pragma unroll
        for (int i = 0; i < 4; ++i) ka[i] = sm.f.sKey[par][i];  // same-address broadcasts
        unsigned long long kk = u64max(u64max(ka[0], ka[1]), u64max(ka[2], ka[3]));
        int far = 8192 - (int)(unsigned)(kk & 0xffffffffull);
        cx = sm.f.ptsx[far];  // uniform LDS broadcast
        cy = sm.f.ptsy[far];
        cz = sm.f.ptsz[far];
    }
    __syncthreads();
    float* ob = newxyz + (size_t)b * 3072;
#pragma unroll
    for (int i = 0; i < 12; ++i) ob[t + 256 * i] = sm.f.cbuf[t + 256 * i];
}

// ---------------- merged ball query: blocks 0..2047 br0 (K=32), 2048..4095 br1 --
__global__ void ball_query2(const float* __restrict__ xyz, const float* __restrict__ newxyz,
                            int* __restrict__ idx0, int* __restrict__ idx1) {
    int bid = blockIdx.x;
    int br = (bid >= 2048);
    int K = br ? 64 : 32;
    float r2 = br ? (0.8f * 0.8f) : (0.4f * 0.4f);
    int* idxout = br ? idx1 : idx0;
    int wid = (((bid & 2047) * 256) + threadIdx.x) >> 6;  // query id, 0..8191
    int lane = threadIdx.x & 63;
    int b = wid >> 10;
    const float* q = newxyz + (size_t)wid * 3;
    float qx = q[0], qy = q[1], qz = q[2];
    const float* xb = xyz + (size_t)b * 8192 * 3;
    int* out = idxout + (size_t)wid * K;
    int count = 0;
    int first = 0;
    for (int base = 0; base < 8192 && count < K; base += 64) {
        int j = base + lane;
        float dx = __fsub_rn(xb[j * 3 + 0], qx);
        float dy = __fsub_rn(xb[j * 3 + 1], qy);
        float dz = __fsub_rn(xb[j * 3 + 2], qz);
        float d2 = __fadd_rn(__fadd_rn(__fmul_rn(dx, dx), __fmul_rn(dy, dy)), __fmul_rn(dz, dz));
        bool in = d2 < r2;
        unsigned long long m = __ballot(in);
        if (count == 0 && m) first = base + __ffsll((long long)m) - 1;
        if (in) {
            int pos = count + __popcll(m & ((1ull << lane) - 1ull));
            if (pos < K) out[pos] = j;
        }
        count += __popcll(m);
    }
    if (count < K) {
        int fillv = (count > 0) ? first : 0;
        for (int p = count + lane; p < K; p += 64) out[p] = fillv;
    }
}

// ---------------- MFMA GEMM, NT n-tiles (NT*16 cols) per block ------------------
// Fragment-major conflict-free LDS staging (R8-proven). NT=16 for MT=1 layers
// (per-column epilogue/staging overhead halves again vs NT=8; LDS 33-53 KB ->
// 3-4 blocks/CU). MT=2 stays NT=8, MT=4 stays NT=4 (VGPR occupancy).
template <int Mp, int Kp, int IN_MODE, int OUT_MODE, int KSH, int NT>
__global__ __launch_bounds__(256) void gemm_mfma(
    const unsigned short* __restrict__ Wb, const unsigned short* __restrict__ Xin,
    const float* __restrict__ aff, const int* __restrict__ idx,
    const unsigned short* __restrict__ ftp, const float* __restrict__ newxyz,
    unsigned short* __restrict__ Yout, float* __restrict__ MX, float* __restrict__ MN,
    float* __restrict__ statS, float* __restrict__ statQ) {
    constexpr int MT = Mp / 64;
    constexpr int KS = Kp / 32;
    constexpr int NC = NT * 16;              // cols per block
    constexpr int NCHUNK = NT * KS * 64;     // 16B chunks in Bs
    __shared__ unsigned short Bs[NCHUNK * 8];
    __shared__ float sAux[NT * 64];          // IN0: idx + 3q per col; IN1: 2*Kp affine
    int* sAuxI = (int*)sAux;

    const int tid = threadIdx.x;
    const int w = tid >> 6;
    const int lane = tid & 63;
    const int n = lane & 15;
    const int quad = lane >> 4;
    const int rbase = w * (Mp / 4);
    const long col0 = (long)blockIdx.x * NC;

    short8 a[MT][KS];
#pragma unroll
    for (int mt = 0; mt < MT; ++mt)
#pragma unroll
        for (int ks = 0; ks < KS; ++ks)
            a[mt][ks] = *(const short8*)(Wb + (size_t)(rbase + mt * 16 + n) * Kp + ks * 32 + quad * 8);

    if constexpr (IN_MODE == 0) {
        for (int c = tid; c < NC; c += 256) {
            long colg = col0 + c;
            sAuxI[c] = idx[colg];
            long sk = colg >> KSH;
            sAux[NC + c] = newxyz[sk * 3 + 0];
            sAux[2 * NC + c] = newxyz[sk * 3 + 1];
            sAux[3 * NC + c] = newxyz[sk * 3 + 2];
        }
    } else {
        if (tid < 2 * Kp) sAux[tid] = aff[tid];
    }
    __syncthreads();

    // ---- Phase 1: build B-tile in LDS, chunk p = i*256+tid (lane-sequential) ----
#pragma unroll
    for (int i = 0; i < NCHUNK / 256; ++i) {
        int p = i * 256 + tid;
        int pl = p & 63;
        int pn = pl & 15;
        int pq = pl >> 4;
        int rest = p >> 6;  // pnt*KS + pks
        int pks = rest % KS;
        int pnt = rest / KS;
        int col = pnt * 16 + pn;
        int kc = pks * 4 + pq;  // 16B chunk index along K
        short8 v;
        if constexpr (IN_MODE == 0) {
            const int bb = (int)(col0 >> (KSH + 10));
            int j = sAuxI[col];
            v = *(const short8*)(ftp + ((long)(bb * 8192 + j)) * 96 + kc * 8);
            if (kc == 0) {  // rel-xyz patch: channels 0..2
                v[0] = (short)f2bf(bf2f((unsigned short)v[0]) - sAux[NC + col]);
                v[1] = (short)f2bf(bf2f((unsigned short)v[1]) - sAux[2 * NC + col]);
                v[2] = (short)f2bf(bf2f((unsigned short)v[2]) - sAux[3 * NC + col]);
            }
        } else {
            short8 raw = *(const short8*)(Xin + (col0 + col) * (long)Kp + kc * 8);
#pragma unroll
            for (int e = 0; e < 8; ++e) {
                float xf = bf2f((unsigned short)raw[e]);
                xf = fmaxf(fmaf(xf, sAux[kc * 8 + e], sAux[Kp + kc * 8 + e]), 0.f);
                v[e] = (short)f2bf(xf);
            }
        }
        *(short8*)(&Bs[p * 8]) = v;
    }
    __syncthreads();

    // ---- Phase 2: MFMA from LDS fragments (lane-sequential ds_read_b128) ----
    f32x4 acc[MT][NT];
#pragma unroll
    for (int mt = 0; mt < MT; ++mt)
#pragma unroll
        for (int nt = 0; nt < NT; ++nt)
#pragma unroll
            for (int r = 0; r < 4; ++r) acc[mt][nt][r] = 0.f;

#pragma unroll
    for (int ks = 0; ks < KS; ++ks) {
#pragma unroll
        for (int nt = 0; nt < NT; ++nt) {
            short8 bfr = *(const short8*)(&Bs[((nt * KS + ks) * 64 + lane) * 8]);
#pragma unroll
            for (int mt = 0; mt < MT; ++mt)
                acc[mt][nt] = __builtin_amdgcn_mfma_f32_16x16x32_bf16(a[mt][ks], bfr, acc[mt][nt], 0, 0, 0);
        }
    }

    // ---- stats: per-channel sum / sumsq ----
    const int slot = (int)(blockIdx.x & 127);
#pragma unroll
    for (int mt = 0; mt < MT; ++mt)
#pragma unroll
        for (int r = 0; r < 4; ++r) {
            float s = 0.f, q = 0.f;
#pragma unroll
            for (int nt = 0; nt < NT; ++nt) {
                float v = acc[mt][nt][r];
                s += v;
                q = fmaf(v, v, q);
            }
#pragma unroll
            for (int off = 1; off < 16; off <<= 1) {
                s += __shfl_xor(s, off, 16);
                q += __shfl_xor(q, off, 16);
            }
            if (n == 0) {
                int ch = rbase + mt * 16 + quad * 4 + r;
                atomicAdd(statS + (size_t)ch * 128 + slot, s);
                atomicAdd(statQ + (size_t)ch * 128 + slot, q);
            }
        }

    if constexpr (OUT_MODE == 0) {
#pragma unroll
        for (int mt = 0; mt < MT; ++mt)
#pragma unroll
            for (int nt = 0; nt < NT; ++nt) {
                long col = col0 + nt * 16 + n;
                unsigned p0 = f2bf(acc[mt][nt][0]) | ((unsigned)f2bf(acc[mt][nt][1]) << 16);
                unsigned p1 = f2bf(acc[mt][nt][2]) | ((unsigned)f2bf(acc[mt][nt][3]) << 16);
                uint2 st; st.x = p0; st.y = p1;
                *(uint2*)(Yout + col * Mp + rbase + mt * 16 + quad * 4) = st;
            }
    } else {
        constexpr int GRP = (1 << KSH) / 16;  // n-tiles per K-sample group (2 or 4)
        constexpr int NG = NT / GRP;          // groups per block
#pragma unroll
        for (int mt = 0; mt < MT; ++mt)
#pragma unroll
            for (int r = 0; r < 4; ++r) {
#pragma unroll
                for (int gh = 0; gh < NG; ++gh) {
                    float mx = acc[mt][GRP * gh][r], mn = acc[mt][GRP * gh][r];
#pragma unroll
                    for (int e = 1; e < GRP; ++e) {
                        mx = fmaxf(mx, acc[mt][GRP * gh + e][r]);
                        mn = fminf(mn, acc[mt][GRP * gh + e][r]);
                    }
#pragma unroll
                    for (int off = 1; off < 16; off <<= 1) {
                        mx = fmaxf(mx, __shfl_xor(mx, off, 16));
                        mn = fminf(mn, __shfl_xor(mn, off, 16));
                    }
                    if (n == 0) {
                        int ch = rbase + mt * 16 + quad * 4 + r;
                        long g = (col0 >> KSH) + gh;
                        MX[(long)ch * 8192 + g] = mx;
                        MN[(long)ch * 8192 + g] = mn;
                    }
                }
            }
    }
}

// ---------------- finalize BN constants ----------------------------------------
__global__ void finalize_kernel(const float* __restrict__ sS, const float* __restrict__ sQ,
                                const float* __restrict__ g, const float* __restrict__ b,
                                float* __restrict__ aff, int C, float invCount) {
    int c = threadIdx.x + blockIdx.x * blockDim.x;
    if (c >= C) return;
    float s = 0.f, q = 0.f;
    for (int k = 0; k < 128; ++k) { s += sS[c * 128 + k]; q += sQ[c * 128 + k]; }
    float mean = s * invCount;
    float var = fmaxf(q * invCount - mean * mean, 0.f);
    float sc = g[c] / sqrtf(var + 1e-5f);
    float sh = b[c] - mean * sc;
    aff[c] = sc;
    aff[C + c] = sh;
}

// ---------------- final output -------------------------------------------------
__global__ void final_out_kernel(const float* __restrict__ MX, const float* __restrict__ MN,
                                 const float* __restrict__ aff, float* __restrict__ out1,
                                 int Cout, int cOff) {
    long i = (long)blockIdx.x * 256 + threadIdx.x;
    int c = (int)(i >> 13);
    int gidx = (int)(i & 8191);
    int b = gidx >> 10, s = gidx & 1023;
    float sc = aff[c], sh = aff[Cout + c];
    float v = fmaxf(fmaxf(sc * MX[i] + sh, sc * MN[i] + sh), 0.f);
    out1[((long)b * 384 + cOff + c) * 1024 + s] = v;
}

// ---------------- host ---------------------------------------------------------
extern "C" void kernel_launch(void* const* d_in, const int* in_sizes, int n_in,
                              void* d_out, int out_size, void* d_ws, size_t ws_size,
                              hipStream_t stream) {
    const float* xyz = (const float*)d_in[0];
    const float* feat = (const float*)d_in[1];
    const float *W[6], *G[6], *Bi[6];
    for (int l = 0; l < 6; ++l) {
        W[l] = (const float*)d_in[2 + l * 3];
        G[l] = (const float*)d_in[3 + l * 3];
        Bi[l] = (const float*)d_in[4 + l * 3];
    }
    char* ws = (char*)d_ws;
    float* out0 = (float*)d_out;
    float* out1 = (float*)d_out + 24576;

    unsigned short* wb = (unsigned short*)(ws + OFF_WBF);
    float* stats = (float*)(ws + OFF_STATS);
    float* affine = (float*)(ws + OFF_AFF);
    int* idx0 = (int*)(ws + OFF_IDX0);
    int* idx1 = (int*)(ws + OFF_IDX1);
    float* mx = (float*)(ws + OFF_MX);
    float* mn = (float*)(ws + OFF_MN);
    unsigned short* y0 = (unsigned short*)(ws + OFF_Y0);
    unsigned short* y1 = (unsigned short*)(ws + OFF_Y1);
    unsigned short* ftp = (unsigned short*)(ws + OFF_FEATT);

    hipMemsetAsync(stats, 0, STATS_BYTES, stream);
    fused_pre<<<1288, 256, 0, stream>>>(xyz, feat, out0, ftp, W[0], W[1], W[2], W[3], W[4],
                                        W[5], wb);
    ball_query2<<<4096, 256, 0, stream>>>(xyz, out0, idx0, idx1);

    const int wOff[6] = {0, 6144, 10240, 18432, 24576, 32768};
    int stOff[6], afOff[6];
    {
        const int Cs[6] = {64, 64, 128, 64, 128, 256};
        int so = 0, ao = 0;
        for (int l = 0; l < 6; ++l) {
            stOff[l] = so; so += Cs[l] * 256;
            afOff[l] = ao; ao += Cs[l] * 2;
        }
    }

    for (int br = 0; br < 2; ++br) {
        const int K = br ? 64 : 32;
        const long NCOL = 8L * 1024 * K;
        int* idx = br ? idx1 : idx0;
        const int l0 = br * 3, l1 = br * 3 + 1, l2 = br * 3 + 2;
        const int M2 = br ? 256 : 128;
        const float invCount = 1.f / (float)NCOL;
        const int nblk256 = (int)(NCOL / 256);
        const int nblk128 = (int)(NCOL / 128);
        const int nblk64 = (int)(NCOL / 64);

        if (br == 0) {
            gemm_mfma<64, 96, 0, 0, 5, 16><<<nblk256, 256, 0, stream>>>(
                wb + wOff[l0], nullptr, nullptr, idx, ftp, out0, y0, nullptr, nullptr,
                stats + stOff[l0], stats + stOff[l0] + 64 * 128);
            finalize_kernel<<<1, 256, 0, stream>>>(stats + stOff[l0], stats + stOff[l0] + 64 * 128,
                                                   G[l0], Bi[l0], affine + afOff[l0], 64, invCount);
            gemm_mfma<64, 64, 1, 0, 5, 16><<<nblk256, 256, 0, stream>>>(
                wb + wOff[l1], y0, affine + afOff[l0], nullptr, nullptr, nullptr, y1, nullptr,
                nullptr, stats + stOff[l1], stats + stOff[l1] + 64 * 128);
            finalize_kernel<<<1, 256, 0, stream>>>(stats + stOff[l1], stats + stOff[l1] + 64 * 128,
                                                   G[l1], Bi[l1], affine + afOff[l1], 64, invCount);
            gemm_mfma<128, 64, 1, 1, 5, 8><<<nblk128, 256, 0, stream>>>(
                wb + wOff[l2], y1, affine + afOff[l1], nullptr, nullptr, nullptr, nullptr, mx, mn,
                stats + stOff[l2], stats + stOff[l2] + 128 * 128);
            finalize_kernel<<<1, 256, 0, stream>>>(stats + stOff[l2], stats + stOff[l2] + 128 * 128,
                                                   G[l2], Bi[l2], affine + afOff[l2], 128, invCount);
        } else {
            gemm_mfma<64, 96, 0, 0, 6, 16><<<nblk256, 256, 0, stream>>>(
                wb + wOff[l0], nullptr, nullptr, idx, ftp, out0, y0, nullptr, nullptr,
                stats + stOff[l0], stats + stOff[l0] + 64 * 128);
            finalize_kernel<<<1, 256, 0, stream>>>(stats + stOff[l0], stats + stOff[l0] + 64 * 128,
                                                   G[l0], Bi[l0], affine + afOff[l0], 64, invCount);
            gemm_mfma<128, 64, 1, 0, 6, 8><<<nblk128, 256, 0, stream>>>(
                wb + wOff[l1], y0, affine + afOff[l0], nullptr, nullptr, nullptr, y1, nullptr,
                nullptr, stats + stOff[l1], stats + stOff[l1] + 128 * 128);
            finalize_kernel<<<1, 256, 0, stream>>>(stats + stOff[l1], stats + stOff[l1] + 128 * 128,
                                                   G[l1], Bi[l1], affine + afOff[l1], 128, invCount);
            gemm_mfma<256, 128, 1, 1, 6, 4><<<nblk64, 256, 0, stream>>>(
                wb + wOff[l2], y1, affine + afOff[l1], nullptr, nullptr, nullptr, nullptr, mx, mn,
                stats + stOff[l2], stats + stOff[l2] + 256 * 128);
            finalize_kernel<<<1, 256, 0, stream>>>(stats + stOff[l2], stats + stOff[l2] + 256 * 128,
                                                   G[l2], Bi[l2], affine + afOff[l2], 256, invCount);
        }

        final_out_kernel<<<(M2 * 8192) / 256, 256, 0, stream>>>(mx, mn, affine + afOff[l2], out1,
                                                                M2, br ? 128 : 0);
    }
}